// Round 8
// baseline (374.970 us; speedup 1.0000x reference)
//
#include <hip/hip_runtime.h>
#include <math.h>

typedef unsigned short ushort_t;
typedef unsigned int uint_t;

#define NIMG 12        // B*N
#define NCH  256       // FC
#define FH   32
#define FW   88
#define NPIX 2816      // FH*FW
#define NDEP 20        // depth bins: 1,4,...,58
#define NOUTC 128
#define NVOX 65536     // 256*256
#define NPTS 675840    // NIMG*NDEP*NPIX
#define NKEY 131072    // 2*NVOX
#define NGP  33792     // NIMG*NPIX
#define BEV_FLOATS 16777216u  // 2*128*65536

// ---- workspace layout (BYTE offsets), total 90099712 ----
// Round-8: segreduce uses ownership semantics (one wave owns each key-run,
// plain stores) -> bevtmp needs NO zeroing at all; garbage in never-written
// rows is masked off in transpose via per-voxel mask_out.
#define B_OCC    0u          // 2048 (per-64-voxel occupancy bytes)
#define B_A1     4096u
#define B_C1     5120u
#define B_A2     6144u
#define B_C2     7168u
#define B_TOT    278528u     // 4
#define B_FEAT   282624u     // bf16 feat: 33792*128*2 = 8650752 -> 8933376
#define B_VCODE  8933376u    // 2703360 -> 11636736
#define B_WT     11636736u   // 2703360 -> 14340096  ([NDEP][NGP] f32)
#define B_CNT    14340096u   // 524288 -> 14864384
#define B_OFFS   14864384u   // 524288 -> 15388672
#define B_CUR    15388672u   // 524288 -> 15912960
#define B_SPINE  15912960u   // 2048  -> 15915008
#define B_RECS   17584128u   // 5406720 -> 22990848
#define B_BEV    22990848u   // 67108864 -> 90099712 (the "hole", never zeroed)
// inside hole (all dead before segreduce writes bevtmp):
#define B_XBF    29972480u   // 17301504
#define B_ACT1   47273984u   // 17301504
#define B_ACT2   64575488u   // 17301504
#define B_WSWZ1  81876992u   // single-bf16: 9*8*16*512*2 = 1179648
#define B_WSWZ2  83056640u   // 1179648
#define B_WSWZ3  84236288u   // split hi/lo: 8*9*2*512*2 = 147456

// fused prep kernel block ranges
#define PREP_W2    2304
#define PREP_W3    4608
#define PREP_BN    4752      // single block
#define PREP_CAST0 4753      // 528 blocks (44 px-chunks x 12 img)
#define PREP_GEOM0 5281      // 2640 blocks
#define PREP_NBLK  7921

// fused gemm+scan block ranges
#define GS_SCAN0   528
#define GS_NBLK    1040      // 528 gemm + 512 scan

typedef __attribute__((ext_vector_type(8))) short bf16x8;
typedef __attribute__((ext_vector_type(4))) float floatx4;
typedef __attribute__((ext_vector_type(4))) uint_t u32x4;

__device__ __forceinline__ ushort_t f2bf(float f) {
    uint_t x = __float_as_uint(f);
    return (ushort_t)((x + 0x7fffu + ((x >> 16) & 1u)) >> 16);
}
__device__ __forceinline__ float bf2f(ushort_t u) {
    return __uint_as_float(((uint_t)u) << 16);
}

__device__ __forceinline__ void inv3x3(const float* __restrict__ M, float* __restrict__ o) {
    float a=M[0],b=M[1],c=M[2],d=M[3],e=M[4],f=M[5],g=M[6],h=M[7],i=M[8];
    float A = e*i - f*h;
    float B = c*h - b*i;
    float C = b*f - c*e;
    float D = f*g - d*i;
    float E = a*i - c*g;
    float F = c*d - a*f;
    float G = d*h - e*g;
    float H = b*g - a*h;
    float I = a*e - b*d;
    float det = a*A + b*D + c*G;
    float id = 1.0f / det;
    o[0]=A*id; o[1]=B*id; o[2]=C*id;
    o[3]=D*id; o[4]=E*id; o[5]=F*id;
    o[6]=G*id; o[7]=H*id; o[8]=I*id;
}

// ---- weight swizzle into MFMA A-fragment order ----
__device__ __forceinline__ void wprep_one(
    const float* __restrict__ w, ushort_t* __restrict__ dst,
    int ntap, int ncib, int ncog, int nco, int nci, int idx, bool split)
{
    int j = idx & 7;
    int l = (idx >> 3) & 63;
    int pairidx = idx >> 9;
    int g = pairidx % ncog;
    int b = (pairidx / ncog) % ncib;
    int t = pairidx / (ncog * ncib);
    int co = g * 16 + (l & 15);
    int ci = b * 32 + (l >> 4) * 8 + j;
    float v = 0.0f;
    if (co < nco) v = w[((size_t)co * nci + ci) * ntap + t];
    ushort_t hi = f2bf(v);
    if (split) {
        dst[(size_t)pairidx * 1024 + l * 8 + j]       = hi;
        dst[(size_t)pairidx * 1024 + 512 + l * 8 + j] = f2bf(v - bf2f(hi));
    } else {
        dst[(size_t)pairidx * 512 + l * 8 + j] = hi;
    }
}

// ---- fused front-end: weight swizzle (3 convs) + BN fold + cast/transpose + geom ----
__global__ __launch_bounds__(256) void prep_all_kernel(
    const float* __restrict__ w1, ushort_t* __restrict__ d1,
    const float* __restrict__ w2, ushort_t* __restrict__ d2,
    const float* __restrict__ w3, ushort_t* __restrict__ d3,
    const float* __restrict__ c2e_rot, const float* __restrict__ c2e_trans,
    const float* __restrict__ intrins, const float* __restrict__ post_rot,
    const float* __restrict__ post_trans,
    const float* __restrict__ c1b, const float* __restrict__ s1,
    const float* __restrict__ bb1, const float* __restrict__ m1, const float* __restrict__ v1,
    const float* __restrict__ c2b, const float* __restrict__ s2,
    const float* __restrict__ bb2, const float* __restrict__ m2, const float* __restrict__ v2,
    float* __restrict__ A1, float* __restrict__ C1,
    float* __restrict__ A2, float* __restrict__ C2,
    const float* __restrict__ img_in, ushort_t* __restrict__ xbf_out,
    int* __restrict__ vcode, uint_t* __restrict__ cnt)
{
    __shared__ __align__(16) ushort_t clds[64 * 264];
    int bid = blockIdx.x;
    int t = threadIdx.x;
    if (bid < PREP_W2) {
        wprep_one(w1, d1, 9, 8, 16, 256, 256, bid * 256 + t, false);
    } else if (bid < PREP_W3) {
        wprep_one(w2, d2, 9, 8, 16, 256, 256, (bid - PREP_W2) * 256 + t, false);
    } else if (bid < PREP_BN) {
        int idx = (bid - PREP_W3) * 256 + t;
        if (idx < 36864) wprep_one(w3, d3, 1, 8, 9, 130, 256, idx, true);
    } else if (bid == PREP_BN) {
        float i1 = s1[t] / sqrtf(v1[t] + 1e-3f);
        A1[t] = i1;
        C1[t] = (c1b[t] - m1[t]) * i1 + bb1[t];
        float i2 = s2[t] / sqrtf(v2[t] + 1e-3f);
        A2[t] = i2;
        C2[t] = (c2b[t] - m2[t]) * i2 + bb2[t];
    } else if (bid < PREP_GEOM0) {
        // cast + transpose img_feats fp32 [img][ci][px] -> bf16 [img*px][ci]
        int cblk = bid - PREP_CAST0;
        int img = cblk / 44;
        int px0 = (cblk - img * 44) * 64;
        const float* src = img_in + (size_t)img * NCH * NPIX;
        int pxl = t & 63;
        int cib = t >> 6;
        #pragma unroll 4
        for (int cc = 0; cc < 64; ++cc) {
            int ci = cc * 4 + cib;
            float v = src[(size_t)ci * NPIX + px0 + pxl];
            clds[pxl * 264 + ci] = f2bf(v);
        }
        __syncthreads();
        int wv = t >> 6, lane = t & 63;
        uint2* outv = (uint2*)xbf_out;
        #pragma unroll
        for (int i = 0; i < 16; ++i) {
            int p = wv * 16 + i;
            uint2 val = *(const uint2*)&clds[p * 264 + lane * 4];
            outv[(size_t)(img * NPIX + px0 + p) * 64 + lane] = val;
        }
    } else {
        // geom: voxel code per frustum point + fused run-length histogram
        int i = (bid - PREP_GEOM0) * 256 + t;
        int lane = t & 63;
        int hw  = i % NPIX;
        int tmp = i / NPIX;
        int d   = tmp % NDEP;
        int bn  = tmp / NDEP;
        int h = hw / FW, w = hw - h * FW;
        float ip[9], ki[9], comb[9];
        inv3x3(post_rot + bn * 9, ip);
        inv3x3(intrins  + bn * 9, ki);
        const float* R = c2e_rot + bn * 9;
        #pragma unroll
        for (int r = 0; r < 3; ++r)
            #pragma unroll
            for (int cc = 0; cc < 3; ++cc)
                comb[r*3+cc] = R[r*3+0]*ki[0*3+cc] + R[r*3+1]*ki[1*3+cc] + R[r*3+2]*ki[2*3+cc];
        float xs = (float)w * (703.0f / 87.0f);
        float ys = (float)h * (255.0f / 31.0f);
        float dv = 1.0f + 3.0f * (float)d;
        float fx = xs - post_trans[bn*3+0];
        float fy = ys - post_trans[bn*3+1];
        float fz = dv - post_trans[bn*3+2];
        float p0 = ip[0]*fx + ip[1]*fy + ip[2]*fz;
        float p1 = ip[3]*fx + ip[4]*fy + ip[5]*fz;
        float p2 = ip[6]*fx + ip[7]*fy + ip[8]*fz;
        p0 *= p2; p1 *= p2;
        float gx = comb[0]*p0 + comb[1]*p1 + comb[2]*p2 + c2e_trans[bn*3+0];
        float gy = comb[3]*p0 + comb[4]*p1 + comb[5]*p2 + c2e_trans[bn*3+1];
        float gz = comb[6]*p0 + comb[7]*p1 + comb[8]*p2 + c2e_trans[bn*3+2];
        const float cx = -51.0f - 0.2f, cy = -51.0f - 0.2f, cz = 0.0f - 10.0f;
        int ix = (int)((gx - cx) / 0.4f);
        int iy = (int)((gy - cy) / 0.4f);
        int iz = (int)((gz - cz) / 20.0f);
        bool kept = (ix >= 0) && (ix < 256) && (iy >= 0) && (iy < 256) && (iz == 0);
        int code = kept ? ((ix << 8) | iy) : -1;
        vcode[i] = code;

        int b = bn / 6;
        uint_t key = kept ? (uint_t)((b << 16) | code) : 0xFFFFFFFFu;
        uint_t prevkey = __shfl_up(key, 1);
        bool leader = (lane == 0) || (key != prevkey);
        unsigned long long mask = __ballot(leader);
        if (leader && kept) {
            unsigned long long higher = mask & ~((2ULL << lane) - 1ULL);
            int nxt = higher ? (__ffsll((long long)higher) - 1) : 64;
            atomicAdd(&cnt[key], (uint_t)(nxt - lane));
        }
    }
}

// ---- 3x3 conv + BN + ReLU via bf16 MFMA (round-6 proven config, exact) ----
// NOTE: two restructures (m=4/n=3 px-split; depth-2 A ring) both regressed;
// this exact structure is the measured best (57.2 us). Do not touch.
__global__ __launch_bounds__(256, 3) void conv3x3_mfma(
    const ushort_t* __restrict__ in,     // [img*2816][256] bf16
    const ushort_t* __restrict__ wswz,   // [9][8][16][64][8] bf16 (single)
    const float* __restrict__ Abn, const float* __restrict__ Cbn,
    ushort_t* __restrict__ out)          // [img*2816][256] bf16
{
    __shared__ __align__(16) ushort_t lds[2][8640];
    int bx = blockIdx.x;            // img*32 + h
    int cg = blockIdx.y;
    int img = bx >> 5, h = bx & 31;
    int t = threadIdx.x;
    int w = t >> 6, l = t & 63;
    int q = l >> 4, c = l & 15;
    const int n0s[6] = {0, 16, 32, 48, 64, 72};

    // zero both buffers once (halo + out-of-range rows stay zero forever)
    for (int i = t; i < 8640; i += 256) ((uint_t*)lds)[i] = 0;

    const u32x4* src4 = (const u32x4*)(in + (size_t)img * NPIX * 256);
    const bf16x8* wsA = (const bf16x8*)wswz;

    // hoisted per-thread staging geometry (5 chunks of 16B per thread), swizzled slot
    int gbase[5], loff[5];
    bool sval[5];
    #pragma unroll
    for (int k = 0; k < 5; ++k) {
        int p = t + k * 256;
        bool valid = (p < 1056);
        int chunk = p >> 2, sub = p & 3;
        int r = chunk / 88;
        int col = chunk - r * 88;
        int hin = h - 1 + r;
        bool inb = valid && (hin >= 0) && (hin < FH);
        sval[k] = inb;
        gbase[k] = inb ? ((hin * 88 + col) * 32 + sub) : 0;
        int cs = col + 1;                         // stored column
        int slot = sub ^ ((cs >> 1) & 3);         // bank swizzle
        loff[k] = ((r * 90 + cs) * 4 + slot) * 8;
    }

    floatx4 acc[2][6];
    #pragma unroll
    for (int m = 0; m < 2; ++m)
        #pragma unroll
        for (int n = 0; n < 6; ++n)
            acc[m][n] = (floatx4){0.f, 0.f, 0.f, 0.f};

    int g0 = cg * 8 + w * 2;

    __syncthreads();                 // zeros visible
    #pragma unroll
    for (int k = 0; k < 5; ++k)
        if (sval[k]) *(u32x4*)&lds[0][loff[k]] = src4[gbase[k]];

    int buf = 0;
    for (int kb = 0; kb < 8; ++kb) {
        __syncthreads();
        u32x4 sreg[5];
        if (kb < 7) {
            #pragma unroll
            for (int k = 0; k < 5; ++k)
                if (sval[k]) sreg[k] = src4[gbase[k] + (kb + 1) * 4];
        }
        const bf16x8* B = (const bf16x8*)lds[buf];

        // A-fragment prefetch, one tap ahead (single bf16 weights)
        bf16x8 a0, a1;
        {
            int pa = (0 * 8 + kb) * 16;
            a0 = wsA[(size_t)(pa + g0    ) * 64 + l];
            a1 = wsA[(size_t)(pa + g0 + 1) * 64 + l];
        }
        #pragma unroll
        for (int t9 = 0; t9 < 9; ++t9) {
            bf16x8 na0, na1;
            if (t9 < 8) {
                int pa = ((t9 + 1) * 8 + kb) * 16;
                na0 = wsA[(size_t)(pa + g0    ) * 64 + l];
                na1 = wsA[(size_t)(pa + g0 + 1) * 64 + l];
            }
            int ky = t9 / 3, kx = t9 - ky * 3;
            #pragma unroll
            for (int n = 0; n < 6; ++n) {
                int col = n0s[n] + kx + c;        // stored column
                int slot = q ^ ((col >> 1) & 3);
                bf16x8 b = B[(ky * 90 + col) * 4 + slot];
                acc[0][n] = __builtin_amdgcn_mfma_f32_16x16x32_bf16(a0, b, acc[0][n], 0, 0, 0);
                acc[1][n] = __builtin_amdgcn_mfma_f32_16x16x32_bf16(a1, b, acc[1][n], 0, 0, 0);
            }
            if (t9 < 8) { a0 = na0; a1 = na1; }
        }
        if (kb < 7) {
            #pragma unroll
            for (int k = 0; k < 5; ++k)
                if (sval[k]) *(u32x4*)&lds[buf ^ 1][loff[k]] = sreg[k];
        }
        buf ^= 1;
    }

    // epilogue: BN + ReLU, store bf16 channel-last
    #pragma unroll
    for (int m = 0; m < 2; ++m) {
        int cob = cg * 128 + w * 32 + m * 16 + q * 4;
        float ba0 = Abn[cob+0], ba1 = Abn[cob+1], ba2 = Abn[cob+2], ba3 = Abn[cob+3];
        float bc0 = Cbn[cob+0], bc1 = Cbn[cob+1], bc2 = Cbn[cob+2], bc3 = Cbn[cob+3];
        #pragma unroll
        for (int n = 0; n < 6; ++n) {
            if (n == 5 && c < 8) continue;
            int col = n0s[n] + c;
            floatx4 v = acc[m][n];
            uint_t lo = (uint_t)f2bf(fmaxf(v[0]*ba0+bc0, 0.f)) | ((uint_t)f2bf(fmaxf(v[1]*ba1+bc1, 0.f)) << 16);
            uint_t hi = (uint_t)f2bf(fmaxf(v[2]*ba2+bc2, 0.f)) | ((uint_t)f2bf(fmaxf(v[3]*ba3+bc3, 0.f)) << 16);
            uint2 val; val.x = lo; val.y = hi;
            *(uint2*)&out[((size_t)img * NPIX + h * 88 + col) * 256 + cob] = val;
        }
    }
}

// ---- fused: 1x1 conv 256->130 (split-bf16) + gaussian weights, and block scan ----
// blocks [0,528): gemm1x1; blocks [528,1040): exclusive scan over cnt.
__global__ __launch_bounds__(256, 4) void gemm_scan_kernel(
    const ushort_t* __restrict__ act2,
    const ushort_t* __restrict__ wswz3,
    const float* __restrict__ b3,
    ushort_t* __restrict__ feat, float* __restrict__ wt,
    const uint_t* __restrict__ cnt, uint_t* __restrict__ offs,
    uint_t* __restrict__ spine)
{
    __shared__ uint_t s[256];
    int t = threadIdx.x;
    if (blockIdx.x >= GS_SCAN0) {
        int blk = blockIdx.x - GS_SCAN0;
        int i = blk * 256 + t;
        uint_t v = cnt[i];
        s[t] = v;
        __syncthreads();
        #pragma unroll
        for (int off = 1; off < 256; off <<= 1) {
            uint_t add = (t >= off) ? s[t - off] : 0u;
            __syncthreads();
            s[t] += add;
            __syncthreads();
        }
        offs[i] = s[t] - v;
        if (t == 255) spine[blk] = s[255];
        return;
    }
    int wv = t >> 6, l = t & 63, q = l >> 4, c = l & 15;
    int n0 = (blockIdx.x * 4 + wv) * 16;
    int px = n0 + c;
    const bf16x8* A = (const bf16x8*)wswz3;
    const bf16x8* B = (const bf16x8*)act2;
    floatx4 acc[9];
    #pragma unroll
    for (int g = 0; g < 9; ++g) acc[g] = (floatx4){0.f, 0.f, 0.f, 0.f};
    for (int kb = 0; kb < 8; ++kb) {
        bf16x8 b = B[(size_t)px * 32 + kb * 4 + q];
        #pragma unroll
        for (int g = 0; g < 9; ++g) {
            size_t pa = (size_t)(kb * 9 + g) * 128;
            acc[g] = __builtin_amdgcn_mfma_f32_16x16x32_bf16(A[pa + l],      b, acc[g], 0, 0, 0);
            acc[g] = __builtin_amdgcn_mfma_f32_16x16x32_bf16(A[pa + 64 + l], b, acc[g], 0, 0, 0);
        }
    }
    // feat store (co 2..129)
    #pragma unroll
    for (int g = 0; g < 9; ++g) {
        #pragma unroll
        for (int r = 0; r < 4; ++r) {
            int co = g * 16 + q * 4 + r;
            if (co < 2 || co >= 130) continue;
            feat[(size_t)px * 128 + (co - 2)] = f2bf(acc[g][r] + b3[co]);
        }
    }
    // fused gaussian depth weights: mu=co0, log_sigma=co1 live on lanes 0..15
    float muv = acc[0][0] + b3[0];
    float lsv = acc[0][1] + b3[1];
    float mu_b  = __shfl(muv, c);               // broadcast from lane c (q==0)
    float sig   = expf(__shfl(lsv, c)) + 1e-6f;
    float ninv2 = -0.5f / (sig * sig);
    float g5[5]; float sum = 0.0f;
    #pragma unroll
    for (int j = 0; j < 5; ++j) {
        float dv = 1.0f + 3.0f * (float)(q * 5 + j);
        float df = dv - mu_b;
        g5[j] = expf(df * df * ninv2);
        sum += g5[j];
    }
    sum += __shfl_xor(sum, 16);
    sum += __shfl_xor(sum, 32);
    float inv = 1.0f / (sum + 1e-6f);
    // wt transposed [NDEP][NGP]: coalesced writes here, coalesced reads in scatter
    #pragma unroll
    for (int j = 0; j < 5; ++j)
        wt[(size_t)(q * 5 + j) * NGP + px] = g5[j] * inv;
}

// ---- fixup: spine prefix, offsets, cursor, mask, total, 64-voxel occupancy ----
__global__ __launch_bounds__(256) void fixup_kernel(
    uint_t* __restrict__ offs, const uint_t* __restrict__ spine,
    uint_t* __restrict__ cursor, const uint_t* __restrict__ cnt,
    float* __restrict__ mask_out, uint_t* __restrict__ total,
    unsigned char* __restrict__ occ)
{
    __shared__ uint_t red[256];
    int bid = blockIdx.x, t = threadIdx.x;
    uint_t part = 0;
    for (int j = t; j < bid; j += 256) part += spine[j];
    red[t] = part;
    __syncthreads();
    #pragma unroll
    for (int off = 128; off > 0; off >>= 1) {
        if (t < off) red[t] += red[t + off];
        __syncthreads();
    }
    uint_t prefix = red[0];
    int i = bid * 256 + t;
    uint_t o = offs[i] + prefix;
    offs[i] = o;
    cursor[i] = o;
    uint_t n = cnt[i];
    mask_out[i] = (n > 0) ? 1.0f : 0.0f;
    // per-64-key occupancy flag (keys are b*65536+voxel; groups match transpose blocks)
    int lane = t & 63, wv = t >> 6;
    unsigned long long any = __ballot(n > 0u);
    if (lane == 0) occ[bid * 4 + wv] = any ? 1 : 0;
    if (i == NKEY - 1) *total = o + n;
}

// ---- scatter with run-length aggregated cursor atomics ----
__global__ __launch_bounds__(256) void scatter_kernel(
    const int* __restrict__ vcode, const float* __restrict__ wt,
    uint_t* __restrict__ cursor, uint2* __restrict__ recs)
{
    int i = blockIdx.x * 256 + threadIdx.x;
    int lane = threadIdx.x & 63;
    int code = vcode[i];
    int hw  = i % NPIX;
    int tmp = i / NPIX;
    int d   = tmp % NDEP;
    int bn  = tmp / NDEP;
    int b   = bn / 6;
    int gp  = bn * NPIX + hw;           // < 33792, fits 16 bits
    bool active = (code >= 0);
    uint_t key = active ? (uint_t)((b << 16) | code) : 0xFFFFFFFFu;
    uint2 r;
    r.x = ((uint_t)(code & 0xffff) << 16) | (uint_t)gp;
    r.y = active ? __float_as_uint(wt[(size_t)d * NGP + gp]) : 0u;   // coalesced

    uint_t prevkey = __shfl_up(key, 1);
    bool leader = (lane == 0) || (key != prevkey);
    unsigned long long mask = __ballot(leader);
    uint_t base = 0;
    if (leader && active) {
        unsigned long long higher = mask & ~((2ULL << lane) - 1ULL);
        int nxt = higher ? (__ffsll((long long)higher) - 1) : 64;
        base = atomicAdd(&cursor[key], (uint_t)(nxt - lane));
    }
    unsigned long long lower = mask & ((2ULL << lane) - 1ULL);
    int lead = 63 - __clzll((long long)lower);   // lower nonzero (lane0 is leader)
    base = __shfl(base, lead);
    if (active) recs[base + (lane - lead)] = r;
}

// ---- segmented reduce, OWNERSHIP semantics: recs is globally sorted by key, so
// each key is one contiguous run. The wave whose 64-chunk contains the run's
// START owns the whole run (walking into later chunks if needed); waves whose
// chunk has no run-start return immediately. Flushes are PLAIN coalesced 512B
// stores (no atomics, no zero-init of bevtmp needed). ----
__global__ __launch_bounds__(256) void segreduce_kernel(
    const uint2* __restrict__ recs, const uint_t* __restrict__ total,
    const uint_t* __restrict__ featu,   // [33792][64] dwords (bf16x2)
    float* __restrict__ bev_tmp)
{
    uint_t R = *total;
    int wid = blockIdx.x * 4 + (threadIdx.x >> 6);
    uint_t start = (uint_t)wid * 64u;
    if (start >= R) return;
    int lane = threadIdx.x & 63;
    uint_t ustart = __builtin_amdgcn_readfirstlane(start);

    // per-lane preload of this chunk's 64 records (one coalesced 512B load)
    uint_t myidx = ustart + (uint_t)lane;
    bool oob = (myidx >= R);
    if (oob) myidx = R - 1u;
    uint2 mr = recs[myidx];

    uint_t mygp  = mr.x & 0xffffu;
    uint_t mykey = ((mygp >= 16896u) ? 0x10000u : 0u) | (mr.x >> 16);

    // previous chunk's last key (uniform scalar load)
    uint_t kprev = 0xFFFFFFFFu;
    if (ustart > 0u) {
        uint2 pr = recs[ustart - 1u];
        uint_t pgp = pr.x & 0xffffu;
        kprev = ((pgp >= 16896u) ? 0x10000u : 0u) | (pr.x >> 16);
    }
    uint_t upkey = (uint_t)__shfl_up((int)mykey, 1);
    if (lane == 0) upkey = kprev;
    bool strans = (!oob) && (mykey != upkey);
    unsigned long long smask = __ballot(strans);
    if (smask == 0ULL) return;          // no run starts here; owned by an earlier wave
    int s0 = __ffsll((long long)smask) - 1;

    uint_t prevk = (uint_t)__shfl((int)mykey, s0);
    float acc0 = 0.f, acc1 = 0.f;

    uint_t fbuf[2][16];
    // prologue: gather batch 0 (branch-free)
    #pragma unroll
    for (int j = 0; j < 16; ++j) {
        uint_t rx = (uint_t)__shfl((int)mr.x, j);
        fbuf[0][j] = featu[(size_t)(rx & 0xffffu) * 64 + lane];
    }
    #pragma unroll
    for (int b = 0; b < 4; ++b) {
        // issue next batch's gathers before the branchy processing of this batch
        if (b < 3) {
            #pragma unroll
            for (int j = 0; j < 16; ++j) {
                uint_t rx = (uint_t)__shfl((int)mr.x, (b + 1) * 16 + j);
                fbuf[(b + 1) & 1][j] = featu[(size_t)(rx & 0xffffu) * 64 + lane];
            }
        }
        #pragma unroll
        for (int j = 0; j < 16; ++j) {
            int e = b * 16 + j;
            uint_t rx = (uint_t)__shfl((int)mr.x, e);
            uint_t ry = (uint_t)__shfl((int)mr.y, e);
            uint_t gp = rx & 0xffffu;
            uint_t key = ((gp >= 16896u) ? 0x10000u : 0u) | (rx >> 16);
            float wv = __uint_as_float(ry);
            if (e < s0) continue;                                    // uniform
            if (ustart + (uint_t)e >= R) { key = prevk; wv = 0.f; }  // uniform
            if (key != prevk) {                                      // uniform
                float* p = bev_tmp + (size_t)prevk * NOUTC;
                float2 st; st.x = acc0; st.y = acc1;
                *(float2*)(p + 2 * lane) = st;                       // plain store
                acc0 = acc1 = 0.f;
                prevk = key;
            }
            uint_t fv = fbuf[b & 1][j];
            acc0 = fmaf(wv, bf2f((ushort_t)(fv & 0xffffu)), acc0);
            acc1 = fmaf(wv, bf2f((ushort_t)(fv >> 16)),     acc1);
        }
    }

    // continuation: the run open at chunk end extends into later chunks; this
    // wave owns it and walks forward in 64-record blocks (batched gathers).
    uint_t cont = ustart + 64u;
    while (cont < R) {
        uint_t ci = cont + (uint_t)lane;
        bool coob = (ci >= R);
        uint2 cr = recs[coob ? (R - 1u) : ci];
        uint_t cgp  = cr.x & 0xffffu;
        uint_t ckey = ((cgp >= 16896u) ? 0x10000u : 0u) | (cr.x >> 16);
        bool stop = coob || (ckey != prevk);
        unsigned long long stopm = __ballot(stop);
        int t1 = stopm ? (__ffsll((long long)stopm) - 1) : 64;
        #pragma unroll
        for (int sb = 0; sb < 4; ++sb) {
            if (sb * 16 >= t1) break;                                // uniform
            uint_t cf[16];
            #pragma unroll
            for (int j = 0; j < 16; ++j) {
                uint_t rx = (uint_t)__shfl((int)cr.x, sb * 16 + j);
                cf[j] = featu[(size_t)(rx & 0xffffu) * 64 + lane];
            }
            #pragma unroll
            for (int j = 0; j < 16; ++j) {
                int e = sb * 16 + j;
                if (e >= t1) break;                                  // uniform
                uint_t ry = (uint_t)__shfl((int)cr.y, e);
                float wv = __uint_as_float(ry);
                uint_t fv = cf[j];
                acc0 = fmaf(wv, bf2f((ushort_t)(fv & 0xffffu)), acc0);
                acc1 = fmaf(wv, bf2f((ushort_t)(fv >> 16)),     acc1);
            }
        }
        if (t1 < 64) break;                                          // uniform
        cont += 64u;
    }
    // final flush of the last owned run
    {
        float* p = bev_tmp + (size_t)prevk * NOUTC;
        float2 st; st.x = acc0; st.y = acc1;
        *(float2*)(p + 2 * lane) = st;
    }
}

// ---- channel-last -> channel-first BEV transpose ----
// occ skips whole empty 64-voxel tiles; mask (per-voxel, from fixup) zeroes
// never-written rows inside occupied tiles (bevtmp is NOT pre-zeroed).
__global__ __launch_bounds__(256) void transpose_kernel(
    const float* __restrict__ bev_tmp, const unsigned char* __restrict__ occ,
    const float* __restrict__ mask, float* __restrict__ bev_out)
{
    __shared__ float lds[64 * 129];
    __shared__ float lmask[64];
    int blk = blockIdx.x;              // 0..2047
    int b   = blk >> 10;
    int v0  = (blk & 1023) * 64;
    int t   = threadIdx.x;
    float* dst = bev_out + (size_t)b * NOUTC * NVOX + v0;
    if (!occ[blk]) {
        // no record touched these 64 voxels: bev rows are exactly zero
        #pragma unroll
        for (int k = 0; k < 32; ++k) {
            int idx = k * 256 + t;
            int vl = idx & 63, ch = idx >> 6;
            dst[(size_t)ch * NVOX + vl] = 0.0f;
        }
        return;
    }
    if (t < 64) lmask[t] = mask[(size_t)b * NVOX + v0 + t];
    __syncthreads();
    const float* src = bev_tmp + ((size_t)b * NVOX + v0) * NOUTC;
    #pragma unroll
    for (int k = 0; k < 32; ++k) {
        int idx = k * 256 + t;
        int v = idx >> 7, ch = idx & 127;
        // select (not multiply): unwritten rows hold garbage (possibly NaN)
        lds[v * 129 + ch] = (lmask[v] != 0.0f) ? src[idx] : 0.0f;
    }
    __syncthreads();
    #pragma unroll
    for (int k = 0; k < 32; ++k) {
        int idx = k * 256 + t;
        int vl = idx & 63, ch = idx >> 6;
        dst[(size_t)ch * NVOX + vl] = lds[vl * 129 + ch];
    }
}

extern "C" void kernel_launch(void* const* d_in, const int* in_sizes, int n_in,
                              void* d_out, int out_size, void* d_ws, size_t ws_size,
                              hipStream_t stream) {
    const float* c2e_rot    = (const float*)d_in[0];
    const float* c2e_trans  = (const float*)d_in[1];
    const float* intrins    = (const float*)d_in[2];
    const float* post_rot   = (const float*)d_in[3];
    const float* post_trans = (const float*)d_in[4];
    const float* img_feats  = (const float*)d_in[5];
    const float* conv1_w    = (const float*)d_in[6];
    const float* conv1_b    = (const float*)d_in[7];
    const float* bn1_s = (const float*)d_in[8];
    const float* bn1_b = (const float*)d_in[9];
    const float* bn1_m = (const float*)d_in[10];
    const float* bn1_v = (const float*)d_in[11];
    const float* conv2_w = (const float*)d_in[12];
    const float* conv2_b = (const float*)d_in[13];
    const float* bn2_s = (const float*)d_in[14];
    const float* bn2_b = (const float*)d_in[15];
    const float* bn2_m = (const float*)d_in[16];
    const float* bn2_v = (const float*)d_in[17];
    const float* conv3_w = (const float*)d_in[18];
    const float* conv3_b = (const float*)d_in[19];

    char* base = (char*)d_ws;
    unsigned char* occ = (unsigned char*)(base + B_OCC);
    float*    A1     = (float*)(base + B_A1);
    float*    C1     = (float*)(base + B_C1);
    float*    A2     = (float*)(base + B_A2);
    float*    C2     = (float*)(base + B_C2);
    uint_t*   total  = (uint_t*)(base + B_TOT);
    ushort_t* feat   = (ushort_t*)(base + B_FEAT);
    uint2*    recs   = (uint2*)(base + B_RECS);
    float*    bevtmp = (float*)(base + B_BEV);
    int*      vcode  = (int*)(base + B_VCODE);
    float*    wt     = (float*)(base + B_WT);
    uint_t*   cnt    = (uint_t*)(base + B_CNT);
    uint_t*   offs   = (uint_t*)(base + B_OFFS);
    uint_t*   cursor = (uint_t*)(base + B_CUR);
    uint_t*   spine  = (uint_t*)(base + B_SPINE);
    ushort_t* xbf    = (ushort_t*)(base + B_XBF);
    ushort_t* act1   = (ushort_t*)(base + B_ACT1);
    ushort_t* act2   = (ushort_t*)(base + B_ACT2);
    ushort_t* wswz1  = (ushort_t*)(base + B_WSWZ1);
    ushort_t* wswz2  = (ushort_t*)(base + B_WSWZ2);
    ushort_t* wswz3  = (ushort_t*)(base + B_WSWZ3);

    float* bev_out  = (float*)d_out;
    float* mask_out = bev_out + BEV_FLOATS;

    hipMemsetAsync(cnt, 0, NKEY * sizeof(uint_t), stream);
    prep_all_kernel<<<PREP_NBLK, 256, 0, stream>>>(
        conv1_w, wswz1, conv2_w, wswz2, conv3_w, wswz3,
        c2e_rot, c2e_trans, intrins, post_rot, post_trans,
        conv1_b, bn1_s, bn1_b, bn1_m, bn1_v,
        conv2_b, bn2_s, bn2_b, bn2_m, bn2_v,
        A1, C1, A2, C2,
        img_feats, xbf, vcode, cnt);
    conv3x3_mfma<<<dim3(NIMG * 32, 2), 256, 0, stream>>>(xbf,  wswz1, A1, C1, act1);
    conv3x3_mfma<<<dim3(NIMG * 32, 2), 256, 0, stream>>>(act1, wswz2, A2, C2, act2);
    gemm_scan_kernel<<<GS_NBLK, 256, 0, stream>>>(act2, wswz3, conv3_b, feat, wt,
                                                  cnt, offs, spine);
    fixup_kernel<<<NKEY / 256, 256, 0, stream>>>(offs, spine, cursor, cnt, mask_out, total, occ);
    scatter_kernel<<<NPTS / 256, 256, 0, stream>>>(vcode, wt, cursor, recs);
    segreduce_kernel<<<(NPTS / 64 + 3) / 4, 256, 0, stream>>>(recs, total, (const uint_t*)feat, bevtmp);
    transpose_kernel<<<2048, 256, 0, stream>>>(bevtmp, occ, mask_out, bev_out);
}

// Round 9
// 339.282 us; speedup vs baseline: 1.1052x; 1.1052x over previous
//
#include <hip/hip_runtime.h>
#include <math.h>

typedef unsigned short ushort_t;
typedef unsigned int uint_t;

#define NIMG 12        // B*N
#define NCH  256       // FC
#define FH   32
#define FW   88
#define NPIX 2816      // FH*FW
#define NDEP 20        // depth bins: 1,4,...,58
#define NOUTC 128
#define NVOX 65536     // 256*256
#define NPTS 675840    // NIMG*NDEP*NPIX
#define NKEY 131072    // 2*NVOX
#define NGP  33792     // NIMG*NPIX
#define BEV_FLOATS 16777216u  // 2*128*65536

// ---- workspace layout (BYTE offsets), total 90099712 ----
// vcode/wt/cnt/offs/cursor/spine live OUT of the bevtmp hole (gap between feat
// and recs) so bevtmp zeroing doesn't anti-depend on scatter's inputs ->
// zeroing fused into the scatter kernel (occupied tiles only).
// NOTE (round-8 lesson): ownership-semantics segreduce (one wave per key-run,
// plain stores, no zeroing) FAILED: voxel runs are power-law skewed (near-camera
// cells collect 1000s of records); single-wave run-walk -> occupancy 13%,
// 28us -> 81us. Chunk-parallel + atomicAdd into zeroed bevtmp is skew-immune.
#define B_OCC    0u          // 2048 (per-64-voxel occupancy bytes)
#define B_A1     4096u
#define B_C1     5120u
#define B_A2     6144u
#define B_C2     7168u
#define B_TOT    278528u     // 4
#define B_FEAT   282624u     // bf16 feat: 33792*128*2 = 8650752 -> 8933376
#define B_VCODE  8933376u    // 2703360 -> 11636736
#define B_WT     11636736u   // 2703360 -> 14340096  ([NDEP][NGP] f32)
#define B_CNT    14340096u   // 524288 -> 14864384
#define B_OFFS   14864384u   // 524288 -> 15388672
#define B_CUR    15388672u   // 524288 -> 15912960
#define B_SPINE  15912960u   // 2048  -> 15915008
#define B_RECS   17584128u   // 5406720 -> 22990848
#define B_BEV    22990848u   // 67108864 -> 90099712 (the "hole")
// inside hole (all dead before scatter runs):
#define B_XBF    29972480u   // 17301504
#define B_ACT1   47273984u   // 17301504
#define B_ACT2   64575488u   // 17301504
#define B_WSWZ1  81876992u   // single-bf16: 9*8*16*512*2 = 1179648
#define B_WSWZ2  83056640u   // 1179648
#define B_WSWZ3  84236288u   // split hi/lo: 8*9*2*512*2 = 147456

// fused prep kernel block ranges
#define PREP_W2    2304
#define PREP_W3    4608
#define PREP_BN    4752      // single block
#define PREP_CAST0 4753      // 528 blocks (44 px-chunks x 12 img)
#define PREP_GEOM0 5281      // 2640 blocks
#define PREP_NBLK  7921

// fused gemm+scan block ranges
#define GS_SCAN0   528
#define GS_NBLK    1040      // 528 gemm + 512 scan

// fused scatter+zero block ranges
#define SCAT_NBLK  2640      // NPTS/256
#define SCATZ_NBLK 4688      // + 2048 zero-tile blocks

typedef __attribute__((ext_vector_type(8))) short bf16x8;
typedef __attribute__((ext_vector_type(4))) float floatx4;
typedef __attribute__((ext_vector_type(4))) uint_t u32x4;

__device__ __forceinline__ ushort_t f2bf(float f) {
    uint_t x = __float_as_uint(f);
    return (ushort_t)((x + 0x7fffu + ((x >> 16) & 1u)) >> 16);
}
__device__ __forceinline__ float bf2f(ushort_t u) {
    return __uint_as_float(((uint_t)u) << 16);
}

__device__ __forceinline__ void inv3x3(const float* __restrict__ M, float* __restrict__ o) {
    float a=M[0],b=M[1],c=M[2],d=M[3],e=M[4],f=M[5],g=M[6],h=M[7],i=M[8];
    float A = e*i - f*h;
    float B = c*h - b*i;
    float C = b*f - c*e;
    float D = f*g - d*i;
    float E = a*i - c*g;
    float F = c*d - a*f;
    float G = d*h - e*g;
    float H = b*g - a*h;
    float I = a*e - b*d;
    float det = a*A + b*D + c*G;
    float id = 1.0f / det;
    o[0]=A*id; o[1]=B*id; o[2]=C*id;
    o[3]=D*id; o[4]=E*id; o[5]=F*id;
    o[6]=G*id; o[7]=H*id; o[8]=I*id;
}

// ---- weight swizzle into MFMA A-fragment order ----
__device__ __forceinline__ void wprep_one(
    const float* __restrict__ w, ushort_t* __restrict__ dst,
    int ntap, int ncib, int ncog, int nco, int nci, int idx, bool split)
{
    int j = idx & 7;
    int l = (idx >> 3) & 63;
    int pairidx = idx >> 9;
    int g = pairidx % ncog;
    int b = (pairidx / ncog) % ncib;
    int t = pairidx / (ncog * ncib);
    int co = g * 16 + (l & 15);
    int ci = b * 32 + (l >> 4) * 8 + j;
    float v = 0.0f;
    if (co < nco) v = w[((size_t)co * nci + ci) * ntap + t];
    ushort_t hi = f2bf(v);
    if (split) {
        dst[(size_t)pairidx * 1024 + l * 8 + j]       = hi;
        dst[(size_t)pairidx * 1024 + 512 + l * 8 + j] = f2bf(v - bf2f(hi));
    } else {
        dst[(size_t)pairidx * 512 + l * 8 + j] = hi;
    }
}

// ---- fused front-end: weight swizzle (3 convs) + BN fold + cast/transpose + geom ----
__global__ __launch_bounds__(256) void prep_all_kernel(
    const float* __restrict__ w1, ushort_t* __restrict__ d1,
    const float* __restrict__ w2, ushort_t* __restrict__ d2,
    const float* __restrict__ w3, ushort_t* __restrict__ d3,
    const float* __restrict__ c2e_rot, const float* __restrict__ c2e_trans,
    const float* __restrict__ intrins, const float* __restrict__ post_rot,
    const float* __restrict__ post_trans,
    const float* __restrict__ c1b, const float* __restrict__ s1,
    const float* __restrict__ bb1, const float* __restrict__ m1, const float* __restrict__ v1,
    const float* __restrict__ c2b, const float* __restrict__ s2,
    const float* __restrict__ bb2, const float* __restrict__ m2, const float* __restrict__ v2,
    float* __restrict__ A1, float* __restrict__ C1,
    float* __restrict__ A2, float* __restrict__ C2,
    const float* __restrict__ img_in, ushort_t* __restrict__ xbf_out,
    int* __restrict__ vcode, uint_t* __restrict__ cnt)
{
    __shared__ __align__(16) ushort_t clds[64 * 264];
    int bid = blockIdx.x;
    int t = threadIdx.x;
    if (bid < PREP_W2) {
        wprep_one(w1, d1, 9, 8, 16, 256, 256, bid * 256 + t, false);
    } else if (bid < PREP_W3) {
        wprep_one(w2, d2, 9, 8, 16, 256, 256, (bid - PREP_W2) * 256 + t, false);
    } else if (bid < PREP_BN) {
        int idx = (bid - PREP_W3) * 256 + t;
        if (idx < 36864) wprep_one(w3, d3, 1, 8, 9, 130, 256, idx, true);
    } else if (bid == PREP_BN) {
        float i1 = s1[t] / sqrtf(v1[t] + 1e-3f);
        A1[t] = i1;
        C1[t] = (c1b[t] - m1[t]) * i1 + bb1[t];
        float i2 = s2[t] / sqrtf(v2[t] + 1e-3f);
        A2[t] = i2;
        C2[t] = (c2b[t] - m2[t]) * i2 + bb2[t];
    } else if (bid < PREP_GEOM0) {
        // cast + transpose img_feats fp32 [img][ci][px] -> bf16 [img*px][ci]
        int cblk = bid - PREP_CAST0;
        int img = cblk / 44;
        int px0 = (cblk - img * 44) * 64;
        const float* src = img_in + (size_t)img * NCH * NPIX;
        int pxl = t & 63;
        int cib = t >> 6;
        #pragma unroll 4
        for (int cc = 0; cc < 64; ++cc) {
            int ci = cc * 4 + cib;
            float v = src[(size_t)ci * NPIX + px0 + pxl];
            clds[pxl * 264 + ci] = f2bf(v);
        }
        __syncthreads();
        int wv = t >> 6, lane = t & 63;
        uint2* outv = (uint2*)xbf_out;
        #pragma unroll
        for (int i = 0; i < 16; ++i) {
            int p = wv * 16 + i;
            uint2 val = *(const uint2*)&clds[p * 264 + lane * 4];
            outv[(size_t)(img * NPIX + px0 + p) * 64 + lane] = val;
        }
    } else {
        // geom: voxel code per frustum point + fused run-length histogram
        int i = (bid - PREP_GEOM0) * 256 + t;
        int lane = t & 63;
        int hw  = i % NPIX;
        int tmp = i / NPIX;
        int d   = tmp % NDEP;
        int bn  = tmp / NDEP;
        int h = hw / FW, w = hw - h * FW;
        float ip[9], ki[9], comb[9];
        inv3x3(post_rot + bn * 9, ip);
        inv3x3(intrins  + bn * 9, ki);
        const float* R = c2e_rot + bn * 9;
        #pragma unroll
        for (int r = 0; r < 3; ++r)
            #pragma unroll
            for (int cc = 0; cc < 3; ++cc)
                comb[r*3+cc] = R[r*3+0]*ki[0*3+cc] + R[r*3+1]*ki[1*3+cc] + R[r*3+2]*ki[2*3+cc];
        float xs = (float)w * (703.0f / 87.0f);
        float ys = (float)h * (255.0f / 31.0f);
        float dv = 1.0f + 3.0f * (float)d;
        float fx = xs - post_trans[bn*3+0];
        float fy = ys - post_trans[bn*3+1];
        float fz = dv - post_trans[bn*3+2];
        float p0 = ip[0]*fx + ip[1]*fy + ip[2]*fz;
        float p1 = ip[3]*fx + ip[4]*fy + ip[5]*fz;
        float p2 = ip[6]*fx + ip[7]*fy + ip[8]*fz;
        p0 *= p2; p1 *= p2;
        float gx = comb[0]*p0 + comb[1]*p1 + comb[2]*p2 + c2e_trans[bn*3+0];
        float gy = comb[3]*p0 + comb[4]*p1 + comb[5]*p2 + c2e_trans[bn*3+1];
        float gz = comb[6]*p0 + comb[7]*p1 + comb[8]*p2 + c2e_trans[bn*3+2];
        const float cx = -51.0f - 0.2f, cy = -51.0f - 0.2f, cz = 0.0f - 10.0f;
        int ix = (int)((gx - cx) / 0.4f);
        int iy = (int)((gy - cy) / 0.4f);
        int iz = (int)((gz - cz) / 20.0f);
        bool kept = (ix >= 0) && (ix < 256) && (iy >= 0) && (iy < 256) && (iz == 0);
        int code = kept ? ((ix << 8) | iy) : -1;
        vcode[i] = code;

        int b = bn / 6;
        uint_t key = kept ? (uint_t)((b << 16) | code) : 0xFFFFFFFFu;
        uint_t prevkey = __shfl_up(key, 1);
        bool leader = (lane == 0) || (key != prevkey);
        unsigned long long mask = __ballot(leader);
        if (leader && kept) {
            unsigned long long higher = mask & ~((2ULL << lane) - 1ULL);
            int nxt = higher ? (__ffsll((long long)higher) - 1) : 64;
            atomicAdd(&cnt[key], (uint_t)(nxt - lane));
        }
    }
}

// ---- 3x3 conv + BN + ReLU via bf16 MFMA (round-6 proven config, exact) ----
// NOTE: two restructures (m=4/n=3 px-split; depth-2 A ring) both regressed;
// this exact structure is the measured best (57.2 us). Do not touch.
__global__ __launch_bounds__(256, 3) void conv3x3_mfma(
    const ushort_t* __restrict__ in,     // [img*2816][256] bf16
    const ushort_t* __restrict__ wswz,   // [9][8][16][64][8] bf16 (single)
    const float* __restrict__ Abn, const float* __restrict__ Cbn,
    ushort_t* __restrict__ out)          // [img*2816][256] bf16
{
    __shared__ __align__(16) ushort_t lds[2][8640];
    int bx = blockIdx.x;            // img*32 + h
    int cg = blockIdx.y;
    int img = bx >> 5, h = bx & 31;
    int t = threadIdx.x;
    int w = t >> 6, l = t & 63;
    int q = l >> 4, c = l & 15;
    const int n0s[6] = {0, 16, 32, 48, 64, 72};

    // zero both buffers once (halo + out-of-range rows stay zero forever)
    for (int i = t; i < 8640; i += 256) ((uint_t*)lds)[i] = 0;

    const u32x4* src4 = (const u32x4*)(in + (size_t)img * NPIX * 256);
    const bf16x8* wsA = (const bf16x8*)wswz;

    // hoisted per-thread staging geometry (5 chunks of 16B per thread), swizzled slot
    int gbase[5], loff[5];
    bool sval[5];
    #pragma unroll
    for (int k = 0; k < 5; ++k) {
        int p = t + k * 256;
        bool valid = (p < 1056);
        int chunk = p >> 2, sub = p & 3;
        int r = chunk / 88;
        int col = chunk - r * 88;
        int hin = h - 1 + r;
        bool inb = valid && (hin >= 0) && (hin < FH);
        sval[k] = inb;
        gbase[k] = inb ? ((hin * 88 + col) * 32 + sub) : 0;
        int cs = col + 1;                         // stored column
        int slot = sub ^ ((cs >> 1) & 3);         // bank swizzle
        loff[k] = ((r * 90 + cs) * 4 + slot) * 8;
    }

    floatx4 acc[2][6];
    #pragma unroll
    for (int m = 0; m < 2; ++m)
        #pragma unroll
        for (int n = 0; n < 6; ++n)
            acc[m][n] = (floatx4){0.f, 0.f, 0.f, 0.f};

    int g0 = cg * 8 + w * 2;

    __syncthreads();                 // zeros visible
    #pragma unroll
    for (int k = 0; k < 5; ++k)
        if (sval[k]) *(u32x4*)&lds[0][loff[k]] = src4[gbase[k]];

    int buf = 0;
    for (int kb = 0; kb < 8; ++kb) {
        __syncthreads();
        u32x4 sreg[5];
        if (kb < 7) {
            #pragma unroll
            for (int k = 0; k < 5; ++k)
                if (sval[k]) sreg[k] = src4[gbase[k] + (kb + 1) * 4];
        }
        const bf16x8* B = (const bf16x8*)lds[buf];

        // A-fragment prefetch, one tap ahead (single bf16 weights)
        bf16x8 a0, a1;
        {
            int pa = (0 * 8 + kb) * 16;
            a0 = wsA[(size_t)(pa + g0    ) * 64 + l];
            a1 = wsA[(size_t)(pa + g0 + 1) * 64 + l];
        }
        #pragma unroll
        for (int t9 = 0; t9 < 9; ++t9) {
            bf16x8 na0, na1;
            if (t9 < 8) {
                int pa = ((t9 + 1) * 8 + kb) * 16;
                na0 = wsA[(size_t)(pa + g0    ) * 64 + l];
                na1 = wsA[(size_t)(pa + g0 + 1) * 64 + l];
            }
            int ky = t9 / 3, kx = t9 - ky * 3;
            #pragma unroll
            for (int n = 0; n < 6; ++n) {
                int col = n0s[n] + kx + c;        // stored column
                int slot = q ^ ((col >> 1) & 3);
                bf16x8 b = B[(ky * 90 + col) * 4 + slot];
                acc[0][n] = __builtin_amdgcn_mfma_f32_16x16x32_bf16(a0, b, acc[0][n], 0, 0, 0);
                acc[1][n] = __builtin_amdgcn_mfma_f32_16x16x32_bf16(a1, b, acc[1][n], 0, 0, 0);
            }
            if (t9 < 8) { a0 = na0; a1 = na1; }
        }
        if (kb < 7) {
            #pragma unroll
            for (int k = 0; k < 5; ++k)
                if (sval[k]) *(u32x4*)&lds[buf ^ 1][loff[k]] = sreg[k];
        }
        buf ^= 1;
    }

    // epilogue: BN + ReLU, store bf16 channel-last
    #pragma unroll
    for (int m = 0; m < 2; ++m) {
        int cob = cg * 128 + w * 32 + m * 16 + q * 4;
        float ba0 = Abn[cob+0], ba1 = Abn[cob+1], ba2 = Abn[cob+2], ba3 = Abn[cob+3];
        float bc0 = Cbn[cob+0], bc1 = Cbn[cob+1], bc2 = Cbn[cob+2], bc3 = Cbn[cob+3];
        #pragma unroll
        for (int n = 0; n < 6; ++n) {
            if (n == 5 && c < 8) continue;
            int col = n0s[n] + c;
            floatx4 v = acc[m][n];
            uint_t lo = (uint_t)f2bf(fmaxf(v[0]*ba0+bc0, 0.f)) | ((uint_t)f2bf(fmaxf(v[1]*ba1+bc1, 0.f)) << 16);
            uint_t hi = (uint_t)f2bf(fmaxf(v[2]*ba2+bc2, 0.f)) | ((uint_t)f2bf(fmaxf(v[3]*ba3+bc3, 0.f)) << 16);
            uint2 val; val.x = lo; val.y = hi;
            *(uint2*)&out[((size_t)img * NPIX + h * 88 + col) * 256 + cob] = val;
        }
    }
}

// ---- fused: 1x1 conv 256->130 (split-bf16) + gaussian weights, and block scan ----
// blocks [0,528): gemm1x1; blocks [528,1040): exclusive scan over cnt.
__global__ __launch_bounds__(256, 4) void gemm_scan_kernel(
    const ushort_t* __restrict__ act2,
    const ushort_t* __restrict__ wswz3,
    const float* __restrict__ b3,
    ushort_t* __restrict__ feat, float* __restrict__ wt,
    const uint_t* __restrict__ cnt, uint_t* __restrict__ offs,
    uint_t* __restrict__ spine)
{
    __shared__ uint_t s[256];
    int t = threadIdx.x;
    if (blockIdx.x >= GS_SCAN0) {
        int blk = blockIdx.x - GS_SCAN0;
        int i = blk * 256 + t;
        uint_t v = cnt[i];
        s[t] = v;
        __syncthreads();
        #pragma unroll
        for (int off = 1; off < 256; off <<= 1) {
            uint_t add = (t >= off) ? s[t - off] : 0u;
            __syncthreads();
            s[t] += add;
            __syncthreads();
        }
        offs[i] = s[t] - v;
        if (t == 255) spine[blk] = s[255];
        return;
    }
    int wv = t >> 6, l = t & 63, q = l >> 4, c = l & 15;
    int n0 = (blockIdx.x * 4 + wv) * 16;
    int px = n0 + c;
    const bf16x8* A = (const bf16x8*)wswz3;
    const bf16x8* B = (const bf16x8*)act2;
    floatx4 acc[9];
    #pragma unroll
    for (int g = 0; g < 9; ++g) acc[g] = (floatx4){0.f, 0.f, 0.f, 0.f};
    for (int kb = 0; kb < 8; ++kb) {
        bf16x8 b = B[(size_t)px * 32 + kb * 4 + q];
        #pragma unroll
        for (int g = 0; g < 9; ++g) {
            size_t pa = (size_t)(kb * 9 + g) * 128;
            acc[g] = __builtin_amdgcn_mfma_f32_16x16x32_bf16(A[pa + l],      b, acc[g], 0, 0, 0);
            acc[g] = __builtin_amdgcn_mfma_f32_16x16x32_bf16(A[pa + 64 + l], b, acc[g], 0, 0, 0);
        }
    }
    // feat store (co 2..129)
    #pragma unroll
    for (int g = 0; g < 9; ++g) {
        #pragma unroll
        for (int r = 0; r < 4; ++r) {
            int co = g * 16 + q * 4 + r;
            if (co < 2 || co >= 130) continue;
            feat[(size_t)px * 128 + (co - 2)] = f2bf(acc[g][r] + b3[co]);
        }
    }
    // fused gaussian depth weights: mu=co0, log_sigma=co1 live on lanes 0..15
    float muv = acc[0][0] + b3[0];
    float lsv = acc[0][1] + b3[1];
    float mu_b  = __shfl(muv, c);               // broadcast from lane c (q==0)
    float sig   = expf(__shfl(lsv, c)) + 1e-6f;
    float ninv2 = -0.5f / (sig * sig);
    float g5[5]; float sum = 0.0f;
    #pragma unroll
    for (int j = 0; j < 5; ++j) {
        float dv = 1.0f + 3.0f * (float)(q * 5 + j);
        float df = dv - mu_b;
        g5[j] = expf(df * df * ninv2);
        sum += g5[j];
    }
    sum += __shfl_xor(sum, 16);
    sum += __shfl_xor(sum, 32);
    float inv = 1.0f / (sum + 1e-6f);
    // wt transposed [NDEP][NGP]: coalesced writes here, coalesced reads in scatter
    #pragma unroll
    for (int j = 0; j < 5; ++j)
        wt[(size_t)(q * 5 + j) * NGP + px] = g5[j] * inv;
}

// ---- fixup: spine prefix, offsets, cursor, mask, total, 64-voxel occupancy ----
__global__ __launch_bounds__(256) void fixup_kernel(
    uint_t* __restrict__ offs, const uint_t* __restrict__ spine,
    uint_t* __restrict__ cursor, const uint_t* __restrict__ cnt,
    float* __restrict__ mask_out, uint_t* __restrict__ total,
    unsigned char* __restrict__ occ)
{
    __shared__ uint_t red[256];
    int bid = blockIdx.x, t = threadIdx.x;
    uint_t part = 0;
    for (int j = t; j < bid; j += 256) part += spine[j];
    red[t] = part;
    __syncthreads();
    #pragma unroll
    for (int off = 128; off > 0; off >>= 1) {
        if (t < off) red[t] += red[t + off];
        __syncthreads();
    }
    uint_t prefix = red[0];
    int i = bid * 256 + t;
    uint_t o = offs[i] + prefix;
    offs[i] = o;
    cursor[i] = o;
    uint_t n = cnt[i];
    mask_out[i] = (n > 0) ? 1.0f : 0.0f;
    // per-64-key occupancy flag (keys are b*65536+voxel; groups match transpose blocks)
    int lane = t & 63, wv = t >> 6;
    unsigned long long any = __ballot(n > 0u);
    if (lane == 0) occ[bid * 4 + wv] = any ? 1 : 0;
    if (i == NKEY - 1) *total = o + n;
}

// ---- fused: scatter (run-length aggregated cursor atomics) + bevtmp zeroing ----
// blocks [0,2640): scatter; blocks [2640,4688): zero one occupied 64-voxel tile
// of bevtmp (32KB). Legal because vcode/wt/cursor no longer alias the hole, and
// everything inside the hole is dead by this dispatch. occ comes from fixup.
__global__ __launch_bounds__(256) void scatter_zero_kernel(
    const int* __restrict__ vcode, const float* __restrict__ wt,
    uint_t* __restrict__ cursor, uint2* __restrict__ recs,
    const unsigned char* __restrict__ occ, float* __restrict__ bev_tmp)
{
    if (blockIdx.x >= SCAT_NBLK) {
        int blk = blockIdx.x - SCAT_NBLK;      // 0..2047
        if (!occ[blk]) return;                 // untouched by segreduce & transpose reads
        int b = blk >> 10;
        int v0 = (blk & 1023) * 64;
        floatx4* dst = (floatx4*)(bev_tmp + ((size_t)b * NVOX + v0) * NOUTC);
        int t = threadIdx.x;
        #pragma unroll
        for (int k = 0; k < 8; ++k)            // 64 vox * 128 ch = 2048 float4
            dst[k * 256 + t] = (floatx4){0.f, 0.f, 0.f, 0.f};
        return;
    }
    int i = blockIdx.x * 256 + threadIdx.x;
    int lane = threadIdx.x & 63;
    int code = vcode[i];
    int hw  = i % NPIX;
    int tmp = i / NPIX;
    int d   = tmp % NDEP;
    int bn  = tmp / NDEP;
    int b   = bn / 6;
    int gp  = bn * NPIX + hw;           // < 33792, fits 16 bits
    bool active = (code >= 0);
    uint_t key = active ? (uint_t)((b << 16) | code) : 0xFFFFFFFFu;
    uint2 r;
    r.x = ((uint_t)(code & 0xffff) << 16) | (uint_t)gp;
    r.y = active ? __float_as_uint(wt[(size_t)d * NGP + gp]) : 0u;   // coalesced

    uint_t prevkey = __shfl_up(key, 1);
    bool leader = (lane == 0) || (key != prevkey);
    unsigned long long mask = __ballot(leader);
    uint_t base = 0;
    if (leader && active) {
        unsigned long long higher = mask & ~((2ULL << lane) - 1ULL);
        int nxt = higher ? (__ffsll((long long)higher) - 1) : 64;
        base = atomicAdd(&cursor[key], (uint_t)(nxt - lane));
    }
    unsigned long long lower = mask & ((2ULL << lane) - 1ULL);
    int lead = 63 - __clzll((long long)lower);   // lower nonzero (lane0 is leader)
    base = __shfl(base, lead);
    if (active) recs[base + (lane - lead)] = r;
}

// ---- segmented reduce: one wave per 64-record chunk; feat is bf16 ----
// Chunk-parallel + atomicAdd into zeroed channel-last bevtmp (skew-immune;
// see round-8 note in the layout comment). 128 atomics span 512B = 8 L2 lines.
__global__ __launch_bounds__(256) void segreduce_kernel(
    const uint2* __restrict__ recs, const uint_t* __restrict__ total,
    const uint_t* __restrict__ featu,   // [33792][64] dwords (bf16x2)
    float* __restrict__ bev_tmp)
{
    uint_t R = *total;
    int wid = blockIdx.x * 4 + (threadIdx.x >> 6);
    uint_t start = (uint_t)wid * 64u;
    if (start >= R) return;
    int lane = threadIdx.x & 63;
    uint_t ustart = __builtin_amdgcn_readfirstlane(start);

    // per-lane preload of this chunk's 64 records (one coalesced 512B load)
    uint_t myidx = ustart + (uint_t)lane;
    if (myidx >= R) myidx = R - 1u;       // clamp; OOB lanes neutralized below
    uint2 mr = recs[myidx];

    uint_t rx0 = (uint_t)__shfl((int)mr.x, 0);
    uint_t gp00 = rx0 & 0xffffu;
    uint_t prevk = ((gp00 >= 16896u) ? 0x10000u : 0u) | (rx0 >> 16);
    float acc0 = 0.f, acc1 = 0.f;

    uint_t fbuf[2][16];
    // prologue: gather batch 0 (branch-free)
    #pragma unroll
    for (int j = 0; j < 16; ++j) {
        uint_t rx = (uint_t)__shfl((int)mr.x, j);
        fbuf[0][j] = featu[(size_t)(rx & 0xffffu) * 64 + lane];
    }
    #pragma unroll
    for (int b = 0; b < 4; ++b) {
        // issue next batch's gathers before the branchy processing of this batch
        if (b < 3) {
            #pragma unroll
            for (int j = 0; j < 16; ++j) {
                uint_t rx = (uint_t)__shfl((int)mr.x, (b + 1) * 16 + j);
                fbuf[(b + 1) & 1][j] = featu[(size_t)(rx & 0xffffu) * 64 + lane];
            }
        }
        #pragma unroll
        for (int j = 0; j < 16; ++j) {
            int e = b * 16 + j;
            uint_t rx = (uint_t)__shfl((int)mr.x, e);
            uint_t ry = (uint_t)__shfl((int)mr.y, e);
            uint_t gp = rx & 0xffffu;
            uint_t key = ((gp >= 16896u) ? 0x10000u : 0u) | (rx >> 16);
            float wv = __uint_as_float(ry);
            if (ustart + (uint_t)e >= R) { key = prevk; wv = 0.f; }   // uniform
            if (key != prevk) {                                       // uniform
                float* p = bev_tmp + (size_t)prevk * NOUTC;
                atomicAdd(p + 2 * lane,     acc0);
                atomicAdd(p + 2 * lane + 1, acc1);
                acc0 = acc1 = 0.f;
                prevk = key;
            }
            uint_t fv = fbuf[b & 1][j];
            acc0 = fmaf(wv, bf2f((ushort_t)(fv & 0xffffu)), acc0);
            acc1 = fmaf(wv, bf2f((ushort_t)(fv >> 16)),     acc1);
        }
    }
    float* p = bev_tmp + (size_t)prevk * NOUTC;
    atomicAdd(p + 2 * lane,     acc0);
    atomicAdd(p + 2 * lane + 1, acc1);
}

// ---- channel-last -> channel-first BEV transpose (skips reads of empty tiles) ----
__global__ __launch_bounds__(256) void transpose_kernel(
    const float* __restrict__ bev_tmp, const unsigned char* __restrict__ occ,
    float* __restrict__ bev_out)
{
    __shared__ float lds[64 * 129];
    int blk = blockIdx.x;              // 0..2047
    int b   = blk >> 10;
    int v0  = (blk & 1023) * 64;
    int t   = threadIdx.x;
    float* dst = bev_out + (size_t)b * NOUTC * NVOX + v0;
    if (!occ[blk]) {
        // no record touched these 64 voxels: bev rows are exactly zero
        #pragma unroll
        for (int k = 0; k < 32; ++k) {
            int idx = k * 256 + t;
            int vl = idx & 63, ch = idx >> 6;
            dst[(size_t)ch * NVOX + vl] = 0.0f;
        }
        return;
    }
    const float* src = bev_tmp + ((size_t)b * NVOX + v0) * NOUTC;
    #pragma unroll
    for (int k = 0; k < 32; ++k) {
        int idx = k * 256 + t;
        int v = idx >> 7, ch = idx & 127;
        lds[v * 129 + ch] = src[idx];
    }
    __syncthreads();
    #pragma unroll
    for (int k = 0; k < 32; ++k) {
        int idx = k * 256 + t;
        int vl = idx & 63, ch = idx >> 6;
        dst[(size_t)ch * NVOX + vl] = lds[vl * 129 + ch];
    }
}

extern "C" void kernel_launch(void* const* d_in, const int* in_sizes, int n_in,
                              void* d_out, int out_size, void* d_ws, size_t ws_size,
                              hipStream_t stream) {
    const float* c2e_rot    = (const float*)d_in[0];
    const float* c2e_trans  = (const float*)d_in[1];
    const float* intrins    = (const float*)d_in[2];
    const float* post_rot   = (const float*)d_in[3];
    const float* post_trans = (const float*)d_in[4];
    const float* img_feats  = (const float*)d_in[5];
    const float* conv1_w    = (const float*)d_in[6];
    const float* conv1_b    = (const float*)d_in[7];
    const float* bn1_s = (const float*)d_in[8];
    const float* bn1_b = (const float*)d_in[9];
    const float* bn1_m = (const float*)d_in[10];
    const float* bn1_v = (const float*)d_in[11];
    const float* conv2_w = (const float*)d_in[12];
    const float* conv2_b = (const float*)d_in[13];
    const float* bn2_s = (const float*)d_in[14];
    const float* bn2_b = (const float*)d_in[15];
    const float* bn2_m = (const float*)d_in[16];
    const float* bn2_v = (const float*)d_in[17];
    const float* conv3_w = (const float*)d_in[18];
    const float* conv3_b = (const float*)d_in[19];

    char* base = (char*)d_ws;
    unsigned char* occ = (unsigned char*)(base + B_OCC);
    float*    A1     = (float*)(base + B_A1);
    float*    C1     = (float*)(base + B_C1);
    float*    A2     = (float*)(base + B_A2);
    float*    C2     = (float*)(base + B_C2);
    uint_t*   total  = (uint_t*)(base + B_TOT);
    ushort_t* feat   = (ushort_t*)(base + B_FEAT);
    uint2*    recs   = (uint2*)(base + B_RECS);
    float*    bevtmp = (float*)(base + B_BEV);
    int*      vcode  = (int*)(base + B_VCODE);
    float*    wt     = (float*)(base + B_WT);
    uint_t*   cnt    = (uint_t*)(base + B_CNT);
    uint_t*   offs   = (uint_t*)(base + B_OFFS);
    uint_t*   cursor = (uint_t*)(base + B_CUR);
    uint_t*   spine  = (uint_t*)(base + B_SPINE);
    ushort_t* xbf    = (ushort_t*)(base + B_XBF);
    ushort_t* act1   = (ushort_t*)(base + B_ACT1);
    ushort_t* act2   = (ushort_t*)(base + B_ACT2);
    ushort_t* wswz1  = (ushort_t*)(base + B_WSWZ1);
    ushort_t* wswz2  = (ushort_t*)(base + B_WSWZ2);
    ushort_t* wswz3  = (ushort_t*)(base + B_WSWZ3);

    float* bev_out  = (float*)d_out;
    float* mask_out = bev_out + BEV_FLOATS;

    hipMemsetAsync(cnt, 0, NKEY * sizeof(uint_t), stream);
    prep_all_kernel<<<PREP_NBLK, 256, 0, stream>>>(
        conv1_w, wswz1, conv2_w, wswz2, conv3_w, wswz3,
        c2e_rot, c2e_trans, intrins, post_rot, post_trans,
        conv1_b, bn1_s, bn1_b, bn1_m, bn1_v,
        conv2_b, bn2_s, bn2_b, bn2_m, bn2_v,
        A1, C1, A2, C2,
        img_feats, xbf, vcode, cnt);
    conv3x3_mfma<<<dim3(NIMG * 32, 2), 256, 0, stream>>>(xbf,  wswz1, A1, C1, act1);
    conv3x3_mfma<<<dim3(NIMG * 32, 2), 256, 0, stream>>>(act1, wswz2, A2, C2, act2);
    gemm_scan_kernel<<<GS_NBLK, 256, 0, stream>>>(act2, wswz3, conv3_b, feat, wt,
                                                  cnt, offs, spine);
    fixup_kernel<<<NKEY / 256, 256, 0, stream>>>(offs, spine, cursor, cnt, mask_out, total, occ);
    scatter_zero_kernel<<<SCATZ_NBLK, 256, 0, stream>>>(vcode, wt, cursor, recs, occ, bevtmp);
    segreduce_kernel<<<(NPTS / 64 + 3) / 4, 256, 0, stream>>>(recs, total, (const uint_t*)feat, bevtmp);
    transpose_kernel<<<2048, 256, 0, stream>>>(bevtmp, occ, bev_out);
}

// Round 10
// 333.773 us; speedup vs baseline: 1.1234x; 1.0165x over previous
//
#include <hip/hip_runtime.h>
#include <math.h>

typedef unsigned short ushort_t;
typedef unsigned int uint_t;

#define NIMG 12        // B*N
#define NCH  256       // FC
#define FH   32
#define FW   88
#define NPIX 2816      // FH*FW
#define NDEP 20        // depth bins: 1,4,...,58
#define NOUTC 128
#define NVOX 65536     // 256*256
#define NPTS 675840    // NIMG*NDEP*NPIX
#define NKEY 131072    // 2*NVOX
#define NGP  33792     // NIMG*NPIX
#define BEV_FLOATS 16777216u  // 2*128*65536

// ---- workspace layout (BYTE offsets), total 90099712 ----
// vcode/wt/cnt/offs/cursor/spine live OUT of the bevtmp hole (gap between feat
// and recs) so bevtmp zeroing doesn't anti-depend on scatter's inputs ->
// zeroing fused into the scatter kernel (occupied tiles only).
// NOTE (round-8 lesson): ownership-semantics segreduce (one wave per key-run,
// plain stores, no zeroing) FAILED: voxel runs are power-law skewed (near-camera
// cells collect 1000s of records); single-wave run-walk -> occupancy 13%,
// 28us -> 81us. Chunk-parallel + atomicAdd into zeroed bevtmp is skew-immune.
#define B_OCC    0u          // 2048 (per-64-voxel occupancy bytes)
#define B_A1     4096u
#define B_C1     5120u
#define B_A2     6144u
#define B_C2     7168u
#define B_TOT    278528u     // 4
#define B_FEAT   282624u     // bf16 feat: 33792*128*2 = 8650752 -> 8933376
#define B_VCODE  8933376u    // 2703360 -> 11636736
#define B_WT     11636736u   // 2703360 -> 14340096  ([NDEP][NGP] f32)
#define B_CNT    14340096u   // 524288 -> 14864384
#define B_OFFS   14864384u   // 524288 -> 15388672
#define B_CUR    15388672u   // 524288 -> 15912960
#define B_SPINE  15912960u   // 2048  -> 15915008
#define B_RECS   17584128u   // 5406720 -> 22990848
#define B_BEV    22990848u   // 67108864 -> 90099712 (the "hole")
// inside hole (all dead before scatter runs):
#define B_XBF    29972480u   // 17301504
#define B_ACT1   47273984u   // 17301504
#define B_ACT2   64575488u   // 17301504
#define B_WSWZ1  81876992u   // single-bf16: 9*8*16*512*2 = 1179648
#define B_WSWZ2  83056640u   // 1179648
#define B_WSWZ3  84236288u   // split hi/lo: 8*9*2*512*2 = 147456

// fused prep kernel block ranges
#define PREP_W2    2304
#define PREP_W3    4608
#define PREP_BN    4752      // single block
#define PREP_CAST0 4753      // 528 blocks (44 px-chunks x 12 img)
#define PREP_GEOM0 5281      // 2640 blocks
#define PREP_NBLK  7921

// fused gemm+scan block ranges
#define GS_SCAN0   528
#define GS_NBLK    1040      // 528 gemm + 512 scan

// fused scatter+zero block ranges
#define SCAT_NBLK  2640      // NPTS/256
#define SCATZ_NBLK 4688      // + 2048 zero-tile blocks

typedef __attribute__((ext_vector_type(8))) short bf16x8;
typedef __attribute__((ext_vector_type(4))) float floatx4;
typedef __attribute__((ext_vector_type(4))) uint_t u32x4;

__device__ __forceinline__ ushort_t f2bf(float f) {
    uint_t x = __float_as_uint(f);
    return (ushort_t)((x + 0x7fffu + ((x >> 16) & 1u)) >> 16);
}
__device__ __forceinline__ float bf2f(ushort_t u) {
    return __uint_as_float(((uint_t)u) << 16);
}

__device__ __forceinline__ void inv3x3(const float* __restrict__ M, float* __restrict__ o) {
    float a=M[0],b=M[1],c=M[2],d=M[3],e=M[4],f=M[5],g=M[6],h=M[7],i=M[8];
    float A = e*i - f*h;
    float B = c*h - b*i;
    float C = b*f - c*e;
    float D = f*g - d*i;
    float E = a*i - c*g;
    float F = c*d - a*f;
    float G = d*h - e*g;
    float H = b*g - a*h;
    float I = a*e - b*d;
    float det = a*A + b*D + c*G;
    float id = 1.0f / det;
    o[0]=A*id; o[1]=B*id; o[2]=C*id;
    o[3]=D*id; o[4]=E*id; o[5]=F*id;
    o[6]=G*id; o[7]=H*id; o[8]=I*id;
}

// ---- weight swizzle into MFMA A-fragment order ----
__device__ __forceinline__ void wprep_one(
    const float* __restrict__ w, ushort_t* __restrict__ dst,
    int ntap, int ncib, int ncog, int nco, int nci, int idx, bool split)
{
    int j = idx & 7;
    int l = (idx >> 3) & 63;
    int pairidx = idx >> 9;
    int g = pairidx % ncog;
    int b = (pairidx / ncog) % ncib;
    int t = pairidx / (ncog * ncib);
    int co = g * 16 + (l & 15);
    int ci = b * 32 + (l >> 4) * 8 + j;
    float v = 0.0f;
    if (co < nco) v = w[((size_t)co * nci + ci) * ntap + t];
    ushort_t hi = f2bf(v);
    if (split) {
        dst[(size_t)pairidx * 1024 + l * 8 + j]       = hi;
        dst[(size_t)pairidx * 1024 + 512 + l * 8 + j] = f2bf(v - bf2f(hi));
    } else {
        dst[(size_t)pairidx * 512 + l * 8 + j] = hi;
    }
}

// ---- fused front-end: weight swizzle (3 convs) + BN fold + cast/transpose + geom ----
__global__ __launch_bounds__(256) void prep_all_kernel(
    const float* __restrict__ w1, ushort_t* __restrict__ d1,
    const float* __restrict__ w2, ushort_t* __restrict__ d2,
    const float* __restrict__ w3, ushort_t* __restrict__ d3,
    const float* __restrict__ c2e_rot, const float* __restrict__ c2e_trans,
    const float* __restrict__ intrins, const float* __restrict__ post_rot,
    const float* __restrict__ post_trans,
    const float* __restrict__ c1b, const float* __restrict__ s1,
    const float* __restrict__ bb1, const float* __restrict__ m1, const float* __restrict__ v1,
    const float* __restrict__ c2b, const float* __restrict__ s2,
    const float* __restrict__ bb2, const float* __restrict__ m2, const float* __restrict__ v2,
    float* __restrict__ A1, float* __restrict__ C1,
    float* __restrict__ A2, float* __restrict__ C2,
    const float* __restrict__ img_in, ushort_t* __restrict__ xbf_out,
    int* __restrict__ vcode, uint_t* __restrict__ cnt)
{
    __shared__ __align__(16) ushort_t clds[64 * 264];
    int bid = blockIdx.x;
    int t = threadIdx.x;
    if (bid < PREP_W2) {
        wprep_one(w1, d1, 9, 8, 16, 256, 256, bid * 256 + t, false);
    } else if (bid < PREP_W3) {
        wprep_one(w2, d2, 9, 8, 16, 256, 256, (bid - PREP_W2) * 256 + t, false);
    } else if (bid < PREP_BN) {
        int idx = (bid - PREP_W3) * 256 + t;
        if (idx < 36864) wprep_one(w3, d3, 1, 8, 9, 130, 256, idx, true);
    } else if (bid == PREP_BN) {
        float i1 = s1[t] / sqrtf(v1[t] + 1e-3f);
        A1[t] = i1;
        C1[t] = (c1b[t] - m1[t]) * i1 + bb1[t];
        float i2 = s2[t] / sqrtf(v2[t] + 1e-3f);
        A2[t] = i2;
        C2[t] = (c2b[t] - m2[t]) * i2 + bb2[t];
    } else if (bid < PREP_GEOM0) {
        // cast + transpose img_feats fp32 [img][ci][px] -> bf16 [img*px][ci]
        int cblk = bid - PREP_CAST0;
        int img = cblk / 44;
        int px0 = (cblk - img * 44) * 64;
        const float* src = img_in + (size_t)img * NCH * NPIX;
        int pxl = t & 63;
        int cib = t >> 6;
        #pragma unroll 4
        for (int cc = 0; cc < 64; ++cc) {
            int ci = cc * 4 + cib;
            float v = src[(size_t)ci * NPIX + px0 + pxl];
            clds[pxl * 264 + ci] = f2bf(v);
        }
        __syncthreads();
        int wv = t >> 6, lane = t & 63;
        uint2* outv = (uint2*)xbf_out;
        #pragma unroll
        for (int i = 0; i < 16; ++i) {
            int p = wv * 16 + i;
            uint2 val = *(const uint2*)&clds[p * 264 + lane * 4];
            outv[(size_t)(img * NPIX + px0 + p) * 64 + lane] = val;
        }
    } else {
        // geom: voxel code per frustum point + fused run-length histogram
        int i = (bid - PREP_GEOM0) * 256 + t;
        int lane = t & 63;
        int hw  = i % NPIX;
        int tmp = i / NPIX;
        int d   = tmp % NDEP;
        int bn  = tmp / NDEP;
        int h = hw / FW, w = hw - h * FW;
        float ip[9], ki[9], comb[9];
        inv3x3(post_rot + bn * 9, ip);
        inv3x3(intrins  + bn * 9, ki);
        const float* R = c2e_rot + bn * 9;
        #pragma unroll
        for (int r = 0; r < 3; ++r)
            #pragma unroll
            for (int cc = 0; cc < 3; ++cc)
                comb[r*3+cc] = R[r*3+0]*ki[0*3+cc] + R[r*3+1]*ki[1*3+cc] + R[r*3+2]*ki[2*3+cc];
        float xs = (float)w * (703.0f / 87.0f);
        float ys = (float)h * (255.0f / 31.0f);
        float dv = 1.0f + 3.0f * (float)d;
        float fx = xs - post_trans[bn*3+0];
        float fy = ys - post_trans[bn*3+1];
        float fz = dv - post_trans[bn*3+2];
        float p0 = ip[0]*fx + ip[1]*fy + ip[2]*fz;
        float p1 = ip[3]*fx + ip[4]*fy + ip[5]*fz;
        float p2 = ip[6]*fx + ip[7]*fy + ip[8]*fz;
        p0 *= p2; p1 *= p2;
        float gx = comb[0]*p0 + comb[1]*p1 + comb[2]*p2 + c2e_trans[bn*3+0];
        float gy = comb[3]*p0 + comb[4]*p1 + comb[5]*p2 + c2e_trans[bn*3+1];
        float gz = comb[6]*p0 + comb[7]*p1 + comb[8]*p2 + c2e_trans[bn*3+2];
        const float cx = -51.0f - 0.2f, cy = -51.0f - 0.2f, cz = 0.0f - 10.0f;
        int ix = (int)((gx - cx) / 0.4f);
        int iy = (int)((gy - cy) / 0.4f);
        int iz = (int)((gz - cz) / 20.0f);
        bool kept = (ix >= 0) && (ix < 256) && (iy >= 0) && (iy < 256) && (iz == 0);
        int code = kept ? ((ix << 8) | iy) : -1;
        vcode[i] = code;

        int b = bn / 6;
        uint_t key = kept ? (uint_t)((b << 16) | code) : 0xFFFFFFFFu;
        uint_t prevkey = __shfl_up(key, 1);
        bool leader = (lane == 0) || (key != prevkey);
        unsigned long long mask = __ballot(leader);
        if (leader && kept) {
            unsigned long long higher = mask & ~((2ULL << lane) - 1ULL);
            int nxt = higher ? (__ffsll((long long)higher) - 1) : 64;
            atomicAdd(&cnt[key], (uint_t)(nxt - lane));
        }
    }
}

// ---- 3x3 conv + BN + ReLU via bf16 MFMA (round-10: merged-cg, m=4) ----
// ONE block per row (grid = img*32), 4 waves, each wave owns 64 output chans
// (m=4 16-co groups), all 6 n-tiles. vs the 2-block round-6 config this halves
// per-row LDS staging AND per-row B-reads (each B read feeds 4 MFMAs) while
// keeping the per-wave A-load RATE at the proven round-0 level (4 loads per
// 24 MFMAs == 2 per 12; round-1's failure was 4 per 12). acc=96 VGPR ->
// launch_bounds(256,2): 2 blocks/CU co-resident (LDS 2x34KB, VGPR 2x~190<512).
__global__ __launch_bounds__(256, 2) void conv3x3_mfma(
    const ushort_t* __restrict__ in,     // [img*2816][256] bf16
    const ushort_t* __restrict__ wswz,   // [9][8][16][64][8] bf16 (single)
    const float* __restrict__ Abn, const float* __restrict__ Cbn,
    ushort_t* __restrict__ out)          // [img*2816][256] bf16
{
    __shared__ __align__(16) ushort_t lds[2][8640];
    int bx = blockIdx.x;            // img*32 + h
    int img = bx >> 5, h = bx & 31;
    int t = threadIdx.x;
    int w = t >> 6, l = t & 63;
    int q = l >> 4, c = l & 15;
    const int n0s[6] = {0, 16, 32, 48, 64, 72};

    // zero both buffers once (halo + out-of-range rows stay zero forever)
    for (int i = t; i < 8640; i += 256) ((uint_t*)lds)[i] = 0;

    const u32x4* src4 = (const u32x4*)(in + (size_t)img * NPIX * 256);
    const bf16x8* wsA = (const bf16x8*)wswz;

    // hoisted per-thread staging geometry (5 chunks of 16B per thread), swizzled slot
    int gbase[5], loff[5];
    bool sval[5];
    #pragma unroll
    for (int k = 0; k < 5; ++k) {
        int p = t + k * 256;
        bool valid = (p < 1056);
        int chunk = p >> 2, sub = p & 3;
        int r = chunk / 88;
        int col = chunk - r * 88;
        int hin = h - 1 + r;
        bool inb = valid && (hin >= 0) && (hin < FH);
        sval[k] = inb;
        gbase[k] = inb ? ((hin * 88 + col) * 32 + sub) : 0;
        int cs = col + 1;                         // stored column
        int slot = sub ^ ((cs >> 1) & 3);         // bank swizzle
        loff[k] = ((r * 90 + cs) * 4 + slot) * 8;
    }

    floatx4 acc[4][6];
    #pragma unroll
    for (int m = 0; m < 4; ++m)
        #pragma unroll
        for (int n = 0; n < 6; ++n)
            acc[m][n] = (floatx4){0.f, 0.f, 0.f, 0.f};

    int g0 = w * 4;                  // wave owns co 16-groups [4w, 4w+4)

    __syncthreads();                 // zeros visible
    #pragma unroll
    for (int k = 0; k < 5; ++k)
        if (sval[k]) *(u32x4*)&lds[0][loff[k]] = src4[gbase[k]];

    int buf = 0;
    for (int kb = 0; kb < 8; ++kb) {
        __syncthreads();
        u32x4 sreg[5];
        if (kb < 7) {
            #pragma unroll
            for (int k = 0; k < 5; ++k)
                if (sval[k]) sreg[k] = src4[gbase[k] + (kb + 1) * 4];
        }
        const bf16x8* B = (const bf16x8*)lds[buf];

        // A-fragment prefetch, one tap ahead (m=4 frags; 4 loads per 24 MFMAs
        // = the proven per-cycle A rate)
        bf16x8 a[4];
        {
            int pa = (0 * 8 + kb) * 16;
            #pragma unroll
            for (int m = 0; m < 4; ++m)
                a[m] = wsA[(size_t)(pa + g0 + m) * 64 + l];
        }
        #pragma unroll
        for (int t9 = 0; t9 < 9; ++t9) {
            bf16x8 na[4];
            if (t9 < 8) {
                int pa = ((t9 + 1) * 8 + kb) * 16;
                #pragma unroll
                for (int m = 0; m < 4; ++m)
                    na[m] = wsA[(size_t)(pa + g0 + m) * 64 + l];
            }
            int ky = t9 / 3, kx = t9 - ky * 3;
            #pragma unroll
            for (int n = 0; n < 6; ++n) {
                int col = n0s[n] + kx + c;        // stored column
                int slot = q ^ ((col >> 1) & 3);
                bf16x8 b = B[(ky * 90 + col) * 4 + slot];
                #pragma unroll
                for (int m = 0; m < 4; ++m)
                    acc[m][n] = __builtin_amdgcn_mfma_f32_16x16x32_bf16(a[m], b, acc[m][n], 0, 0, 0);
            }
            if (t9 < 8) {
                #pragma unroll
                for (int m = 0; m < 4; ++m) a[m] = na[m];
            }
        }
        if (kb < 7) {
            #pragma unroll
            for (int k = 0; k < 5; ++k)
                if (sval[k]) *(u32x4*)&lds[buf ^ 1][loff[k]] = sreg[k];
        }
        buf ^= 1;
    }

    // epilogue: BN + ReLU, store bf16 channel-last
    #pragma unroll
    for (int m = 0; m < 4; ++m) {
        int cob = w * 64 + m * 16 + q * 4;
        float ba0 = Abn[cob+0], ba1 = Abn[cob+1], ba2 = Abn[cob+2], ba3 = Abn[cob+3];
        float bc0 = Cbn[cob+0], bc1 = Cbn[cob+1], bc2 = Cbn[cob+2], bc3 = Cbn[cob+3];
        #pragma unroll
        for (int n = 0; n < 6; ++n) {
            if (n == 5 && c < 8) continue;
            int col = n0s[n] + c;
            floatx4 v = acc[m][n];
            uint_t lo = (uint_t)f2bf(fmaxf(v[0]*ba0+bc0, 0.f)) | ((uint_t)f2bf(fmaxf(v[1]*ba1+bc1, 0.f)) << 16);
            uint_t hi = (uint_t)f2bf(fmaxf(v[2]*ba2+bc2, 0.f)) | ((uint_t)f2bf(fmaxf(v[3]*ba3+bc3, 0.f)) << 16);
            uint2 val; val.x = lo; val.y = hi;
            *(uint2*)&out[((size_t)img * NPIX + h * 88 + col) * 256 + cob] = val;
        }
    }
}

// ---- fused: 1x1 conv 256->130 (split-bf16) + gaussian weights, and block scan ----
// blocks [0,528): gemm1x1; blocks [528,1040): exclusive scan over cnt.
__global__ __launch_bounds__(256, 4) void gemm_scan_kernel(
    const ushort_t* __restrict__ act2,
    const ushort_t* __restrict__ wswz3,
    const float* __restrict__ b3,
    ushort_t* __restrict__ feat, float* __restrict__ wt,
    const uint_t* __restrict__ cnt, uint_t* __restrict__ offs,
    uint_t* __restrict__ spine)
{
    __shared__ uint_t s[256];
    int t = threadIdx.x;
    if (blockIdx.x >= GS_SCAN0) {
        int blk = blockIdx.x - GS_SCAN0;
        int i = blk * 256 + t;
        uint_t v = cnt[i];
        s[t] = v;
        __syncthreads();
        #pragma unroll
        for (int off = 1; off < 256; off <<= 1) {
            uint_t add = (t >= off) ? s[t - off] : 0u;
            __syncthreads();
            s[t] += add;
            __syncthreads();
        }
        offs[i] = s[t] - v;
        if (t == 255) spine[blk] = s[255];
        return;
    }
    int wv = t >> 6, l = t & 63, q = l >> 4, c = l & 15;
    int n0 = (blockIdx.x * 4 + wv) * 16;
    int px = n0 + c;
    const bf16x8* A = (const bf16x8*)wswz3;
    const bf16x8* B = (const bf16x8*)act2;
    floatx4 acc[9];
    #pragma unroll
    for (int g = 0; g < 9; ++g) acc[g] = (floatx4){0.f, 0.f, 0.f, 0.f};
    for (int kb = 0; kb < 8; ++kb) {
        bf16x8 b = B[(size_t)px * 32 + kb * 4 + q];
        #pragma unroll
        for (int g = 0; g < 9; ++g) {
            size_t pa = (size_t)(kb * 9 + g) * 128;
            acc[g] = __builtin_amdgcn_mfma_f32_16x16x32_bf16(A[pa + l],      b, acc[g], 0, 0, 0);
            acc[g] = __builtin_amdgcn_mfma_f32_16x16x32_bf16(A[pa + 64 + l], b, acc[g], 0, 0, 0);
        }
    }
    // feat store (co 2..129)
    #pragma unroll
    for (int g = 0; g < 9; ++g) {
        #pragma unroll
        for (int r = 0; r < 4; ++r) {
            int co = g * 16 + q * 4 + r;
            if (co < 2 || co >= 130) continue;
            feat[(size_t)px * 128 + (co - 2)] = f2bf(acc[g][r] + b3[co]);
        }
    }
    // fused gaussian depth weights: mu=co0, log_sigma=co1 live on lanes 0..15
    float muv = acc[0][0] + b3[0];
    float lsv = acc[0][1] + b3[1];
    float mu_b  = __shfl(muv, c);               // broadcast from lane c (q==0)
    float sig   = expf(__shfl(lsv, c)) + 1e-6f;
    float ninv2 = -0.5f / (sig * sig);
    float g5[5]; float sum = 0.0f;
    #pragma unroll
    for (int j = 0; j < 5; ++j) {
        float dv = 1.0f + 3.0f * (float)(q * 5 + j);
        float df = dv - mu_b;
        g5[j] = expf(df * df * ninv2);
        sum += g5[j];
    }
    sum += __shfl_xor(sum, 16);
    sum += __shfl_xor(sum, 32);
    float inv = 1.0f / (sum + 1e-6f);
    // wt transposed [NDEP][NGP]: coalesced writes here, coalesced reads in scatter
    #pragma unroll
    for (int j = 0; j < 5; ++j)
        wt[(size_t)(q * 5 + j) * NGP + px] = g5[j] * inv;
}

// ---- fixup: spine prefix, offsets, cursor, mask, total, 64-voxel occupancy ----
__global__ __launch_bounds__(256) void fixup_kernel(
    uint_t* __restrict__ offs, const uint_t* __restrict__ spine,
    uint_t* __restrict__ cursor, const uint_t* __restrict__ cnt,
    float* __restrict__ mask_out, uint_t* __restrict__ total,
    unsigned char* __restrict__ occ)
{
    __shared__ uint_t red[256];
    int bid = blockIdx.x, t = threadIdx.x;
    uint_t part = 0;
    for (int j = t; j < bid; j += 256) part += spine[j];
    red[t] = part;
    __syncthreads();
    #pragma unroll
    for (int off = 128; off > 0; off >>= 1) {
        if (t < off) red[t] += red[t + off];
        __syncthreads();
    }
    uint_t prefix = red[0];
    int i = bid * 256 + t;
    uint_t o = offs[i] + prefix;
    offs[i] = o;
    cursor[i] = o;
    uint_t n = cnt[i];
    mask_out[i] = (n > 0) ? 1.0f : 0.0f;
    // per-64-key occupancy flag (keys are b*65536+voxel; groups match transpose blocks)
    int lane = t & 63, wv = t >> 6;
    unsigned long long any = __ballot(n > 0u);
    if (lane == 0) occ[bid * 4 + wv] = any ? 1 : 0;
    if (i == NKEY - 1) *total = o + n;
}

// ---- fused: scatter (run-length aggregated cursor atomics) + bevtmp zeroing ----
// blocks [0,2640): scatter; blocks [2640,4688): zero one occupied 64-voxel tile
// of bevtmp (32KB). Legal because vcode/wt/cursor no longer alias the hole, and
// everything inside the hole is dead by this dispatch. occ comes from fixup.
__global__ __launch_bounds__(256) void scatter_zero_kernel(
    const int* __restrict__ vcode, const float* __restrict__ wt,
    uint_t* __restrict__ cursor, uint2* __restrict__ recs,
    const unsigned char* __restrict__ occ, float* __restrict__ bev_tmp)
{
    if (blockIdx.x >= SCAT_NBLK) {
        int blk = blockIdx.x - SCAT_NBLK;      // 0..2047
        if (!occ[blk]) return;                 // untouched by segreduce & transpose reads
        int b = blk >> 10;
        int v0 = (blk & 1023) * 64;
        floatx4* dst = (floatx4*)(bev_tmp + ((size_t)b * NVOX + v0) * NOUTC);
        int t = threadIdx.x;
        #pragma unroll
        for (int k = 0; k < 8; ++k)            // 64 vox * 128 ch = 2048 float4
            dst[k * 256 + t] = (floatx4){0.f, 0.f, 0.f, 0.f};
        return;
    }
    int i = blockIdx.x * 256 + threadIdx.x;
    int lane = threadIdx.x & 63;
    int code = vcode[i];
    int hw  = i % NPIX;
    int tmp = i / NPIX;
    int d   = tmp % NDEP;
    int bn  = tmp / NDEP;
    int b   = bn / 6;
    int gp  = bn * NPIX + hw;           // < 33792, fits 16 bits
    bool active = (code >= 0);
    uint_t key = active ? (uint_t)((b << 16) | code) : 0xFFFFFFFFu;
    uint2 r;
    r.x = ((uint_t)(code & 0xffff) << 16) | (uint_t)gp;
    r.y = active ? __float_as_uint(wt[(size_t)d * NGP + gp]) : 0u;   // coalesced

    uint_t prevkey = __shfl_up(key, 1);
    bool leader = (lane == 0) || (key != prevkey);
    unsigned long long mask = __ballot(leader);
    uint_t base = 0;
    if (leader && active) {
        unsigned long long higher = mask & ~((2ULL << lane) - 1ULL);
        int nxt = higher ? (__ffsll((long long)higher) - 1) : 64;
        base = atomicAdd(&cursor[key], (uint_t)(nxt - lane));
    }
    unsigned long long lower = mask & ((2ULL << lane) - 1ULL);
    int lead = 63 - __clzll((long long)lower);   // lower nonzero (lane0 is leader)
    base = __shfl(base, lead);
    if (active) recs[base + (lane - lead)] = r;
}

// ---- segmented reduce: one wave per 64-record chunk; feat is bf16 ----
// Chunk-parallel + atomicAdd into zeroed channel-last bevtmp (skew-immune;
// see round-8 note in the layout comment). 128 atomics span 512B = 8 L2 lines.
__global__ __launch_bounds__(256) void segreduce_kernel(
    const uint2* __restrict__ recs, const uint_t* __restrict__ total,
    const uint_t* __restrict__ featu,   // [33792][64] dwords (bf16x2)
    float* __restrict__ bev_tmp)
{
    uint_t R = *total;
    int wid = blockIdx.x * 4 + (threadIdx.x >> 6);
    uint_t start = (uint_t)wid * 64u;
    if (start >= R) return;
    int lane = threadIdx.x & 63;
    uint_t ustart = __builtin_amdgcn_readfirstlane(start);

    // per-lane preload of this chunk's 64 records (one coalesced 512B load)
    uint_t myidx = ustart + (uint_t)lane;
    if (myidx >= R) myidx = R - 1u;       // clamp; OOB lanes neutralized below
    uint2 mr = recs[myidx];

    uint_t rx0 = (uint_t)__shfl((int)mr.x, 0);
    uint_t gp00 = rx0 & 0xffffu;
    uint_t prevk = ((gp00 >= 16896u) ? 0x10000u : 0u) | (rx0 >> 16);
    float acc0 = 0.f, acc1 = 0.f;

    uint_t fbuf[2][16];
    // prologue: gather batch 0 (branch-free)
    #pragma unroll
    for (int j = 0; j < 16; ++j) {
        uint_t rx = (uint_t)__shfl((int)mr.x, j);
        fbuf[0][j] = featu[(size_t)(rx & 0xffffu) * 64 + lane];
    }
    #pragma unroll
    for (int b = 0; b < 4; ++b) {
        // issue next batch's gathers before the branchy processing of this batch
        if (b < 3) {
            #pragma unroll
            for (int j = 0; j < 16; ++j) {
                uint_t rx = (uint_t)__shfl((int)mr.x, (b + 1) * 16 + j);
                fbuf[(b + 1) & 1][j] = featu[(size_t)(rx & 0xffffu) * 64 + lane];
            }
        }
        #pragma unroll
        for (int j = 0; j < 16; ++j) {
            int e = b * 16 + j;
            uint_t rx = (uint_t)__shfl((int)mr.x, e);
            uint_t ry = (uint_t)__shfl((int)mr.y, e);
            uint_t gp = rx & 0xffffu;
            uint_t key = ((gp >= 16896u) ? 0x10000u : 0u) | (rx >> 16);
            float wv = __uint_as_float(ry);
            if (ustart + (uint_t)e >= R) { key = prevk; wv = 0.f; }   // uniform
            if (key != prevk) {                                       // uniform
                float* p = bev_tmp + (size_t)prevk * NOUTC;
                atomicAdd(p + 2 * lane,     acc0);
                atomicAdd(p + 2 * lane + 1, acc1);
                acc0 = acc1 = 0.f;
                prevk = key;
            }
            uint_t fv = fbuf[b & 1][j];
            acc0 = fmaf(wv, bf2f((ushort_t)(fv & 0xffffu)), acc0);
            acc1 = fmaf(wv, bf2f((ushort_t)(fv >> 16)),     acc1);
        }
    }
    float* p = bev_tmp + (size_t)prevk * NOUTC;
    atomicAdd(p + 2 * lane,     acc0);
    atomicAdd(p + 2 * lane + 1, acc1);
}

// ---- channel-last -> channel-first BEV transpose (skips reads of empty tiles) ----
__global__ __launch_bounds__(256) void transpose_kernel(
    const float* __restrict__ bev_tmp, const unsigned char* __restrict__ occ,
    float* __restrict__ bev_out)
{
    __shared__ float lds[64 * 129];
    int blk = blockIdx.x;              // 0..2047
    int b   = blk >> 10;
    int v0  = (blk & 1023) * 64;
    int t   = threadIdx.x;
    float* dst = bev_out + (size_t)b * NOUTC * NVOX + v0;
    if (!occ[blk]) {
        // no record touched these 64 voxels: bev rows are exactly zero
        #pragma unroll
        for (int k = 0; k < 32; ++k) {
            int idx = k * 256 + t;
            int vl = idx & 63, ch = idx >> 6;
            dst[(size_t)ch * NVOX + vl] = 0.0f;
        }
        return;
    }
    const float* src = bev_tmp + ((size_t)b * NVOX + v0) * NOUTC;
    #pragma unroll
    for (int k = 0; k < 32; ++k) {
        int idx = k * 256 + t;
        int v = idx >> 7, ch = idx & 127;
        lds[v * 129 + ch] = src[idx];
    }
    __syncthreads();
    #pragma unroll
    for (int k = 0; k < 32; ++k) {
        int idx = k * 256 + t;
        int vl = idx & 63, ch = idx >> 6;
        dst[(size_t)ch * NVOX + vl] = lds[vl * 129 + ch];
    }
}

extern "C" void kernel_launch(void* const* d_in, const int* in_sizes, int n_in,
                              void* d_out, int out_size, void* d_ws, size_t ws_size,
                              hipStream_t stream) {
    const float* c2e_rot    = (const float*)d_in[0];
    const float* c2e_trans  = (const float*)d_in[1];
    const float* intrins    = (const float*)d_in[2];
    const float* post_rot   = (const float*)d_in[3];
    const float* post_trans = (const float*)d_in[4];
    const float* img_feats  = (const float*)d_in[5];
    const float* conv1_w    = (const float*)d_in[6];
    const float* conv1_b    = (const float*)d_in[7];
    const float* bn1_s = (const float*)d_in[8];
    const float* bn1_b = (const float*)d_in[9];
    const float* bn1_m = (const float*)d_in[10];
    const float* bn1_v = (const float*)d_in[11];
    const float* conv2_w = (const float*)d_in[12];
    const float* conv2_b = (const float*)d_in[13];
    const float* bn2_s = (const float*)d_in[14];
    const float* bn2_b = (const float*)d_in[15];
    const float* bn2_m = (const float*)d_in[16];
    const float* bn2_v = (const float*)d_in[17];
    const float* conv3_w = (const float*)d_in[18];
    const float* conv3_b = (const float*)d_in[19];

    char* base = (char*)d_ws;
    unsigned char* occ = (unsigned char*)(base + B_OCC);
    float*    A1     = (float*)(base + B_A1);
    float*    C1     = (float*)(base + B_C1);
    float*    A2     = (float*)(base + B_A2);
    float*    C2     = (float*)(base + B_C2);
    uint_t*   total  = (uint_t*)(base + B_TOT);
    ushort_t* feat   = (ushort_t*)(base + B_FEAT);
    uint2*    recs   = (uint2*)(base + B_RECS);
    float*    bevtmp = (float*)(base + B_BEV);
    int*      vcode  = (int*)(base + B_VCODE);
    float*    wt     = (float*)(base + B_WT);
    uint_t*   cnt    = (uint_t*)(base + B_CNT);
    uint_t*   offs   = (uint_t*)(base + B_OFFS);
    uint_t*   cursor = (uint_t*)(base + B_CUR);
    uint_t*   spine  = (uint_t*)(base + B_SPINE);
    ushort_t* xbf    = (ushort_t*)(base + B_XBF);
    ushort_t* act1   = (ushort_t*)(base + B_ACT1);
    ushort_t* act2   = (ushort_t*)(base + B_ACT2);
    ushort_t* wswz1  = (ushort_t*)(base + B_WSWZ1);
    ushort_t* wswz2  = (ushort_t*)(base + B_WSWZ2);
    ushort_t* wswz3  = (ushort_t*)(base + B_WSWZ3);

    float* bev_out  = (float*)d_out;
    float* mask_out = bev_out + BEV_FLOATS;

    hipMemsetAsync(cnt, 0, NKEY * sizeof(uint_t), stream);
    prep_all_kernel<<<PREP_NBLK, 256, 0, stream>>>(
        conv1_w, wswz1, conv2_w, wswz2, conv3_w, wswz3,
        c2e_rot, c2e_trans, intrins, post_rot, post_trans,
        conv1_b, bn1_s, bn1_b, bn1_m, bn1_v,
        conv2_b, bn2_s, bn2_b, bn2_m, bn2_v,
        A1, C1, A2, C2,
        img_feats, xbf, vcode, cnt);
    conv3x3_mfma<<<NIMG * 32, 256, 0, stream>>>(xbf,  wswz1, A1, C1, act1);
    conv3x3_mfma<<<NIMG * 32, 256, 0, stream>>>(act1, wswz2, A2, C2, act2);
    gemm_scan_kernel<<<GS_NBLK, 256, 0, stream>>>(act2, wswz3, conv3_b, feat, wt,
                                                  cnt, offs, spine);
    fixup_kernel<<<NKEY / 256, 256, 0, stream>>>(offs, spine, cursor, cnt, mask_out, total, occ);
    scatter_zero_kernel<<<SCATZ_NBLK, 256, 0, stream>>>(vcode, wt, cursor, recs, occ, bevtmp);
    segreduce_kernel<<<(NPTS / 64 + 3) / 4, 256, 0, stream>>>(recs, total, (const uint_t*)feat, bevtmp);
    transpose_kernel<<<2048, 256, 0, stream>>>(bevtmp, occ, bev_out);
}